// Round 3
// baseline (584.882 us; speedup 1.0000x reference)
//
#include <hip/hip_runtime.h>
#include <hip/hip_fp16.h>
#include <math.h>

#define PI_F 3.14159265358979323846f

// ---------------- fast atan2 (minimax deg-11, max err ~1e-5 rad) ----------------
// Note: poly(a) >= 0 for a in [0,1], so |result| <= pi exactly (needed by the
// clamp-only bilinear edge handling in photo_scale4).
__device__ inline float fast_atan2f(float y, float x) {
    float ax = fabsf(x), ay = fabsf(y);
    float mx = fmaxf(ax, ay);
    float mn = fminf(ax, ay);
    float a = __fdividef(mn, fmaxf(mx, 1e-30f));
    float s = a * a;
    float r = fmaf(s, fmaf(s, fmaf(s, fmaf(s, fmaf(s, -0.01172120f, 0.05265332f),
                   -0.11643287f), 0.19354346f), -0.33262347f), 0.99997726f);
    r = r * a;
    if (ay > ax) r = 1.57079632679f - r;
    if (x < 0.0f) r = PI_F - r;
    return copysignf(r, y);
}

// Rodrigues: pose (tx,ty,tz,rx,ry,rz) -> o[0..8]=R row-major, o[9..11]=t
__device__ inline void make_Rt_to(const float* __restrict__ pose, int bn, float* __restrict__ o) {
    const float* p = pose + bn * 6;
    float tx = p[0], ty = p[1], tz = p[2];
    float rx = p[3], ry = p[4], rz = p[5];
    float theta = sqrtf(rx * rx + ry * ry + rz * rz);
    float inv = __fdividef(1.0f, fmaxf(theta, 1e-8f));
    float kx = rx * inv, ky = ry * inv, kz = rz * inv;
    float s, c;
    __sincosf(theta, &s, &c);
    float oc = 1.0f - c;
    o[0] = 1.0f - oc * (ky * ky + kz * kz);
    o[1] = -s * kz + oc * kx * ky;
    o[2] =  s * ky + oc * kx * kz;
    o[3] =  s * kz + oc * kx * ky;
    o[4] = 1.0f - oc * (kx * kx + kz * kz);
    o[5] = -s * kx + oc * ky * kz;
    o[6] = -s * ky + oc * kx * kz;
    o[7] =  s * kx + oc * ky * kz;
    o[8] = 1.0f - oc * (kx * kx + ky * ky);
    o[9] = tx; o[10] = ty; o[11] = tz;
}

// ---------------- 11-11-10 fixed-point RGB packing (4 B / pixel) ----------------
__device__ inline unsigned pack_px1(float r, float g, float b) {
    unsigned ri = __float2uint_rn(__saturatef(r) * 2047.0f);
    unsigned gi = __float2uint_rn(__saturatef(g) * 2047.0f);
    unsigned bi = __float2uint_rn(__saturatef(b) * 1023.0f);
    return ri | (gi << 11) | (bi << 22);
}
__device__ inline float3 unpack_px1(unsigned u) {
    float r = (float)(u & 2047u) * (1.0f / 2047.0f);
    float g = (float)((u >> 11) & 2047u) * (1.0f / 2047.0f);
    float b = (float)(u >> 22) * (1.0f / 1023.0f);
    return make_float3(r, g, b);
}

// ---------------- prep: streaming row-band pass (also zeroes out[0]) -----------
__global__ __launch_bounds__(256) void prep_kernel(
    const float* __restrict__ ref, const float* __restrict__ tgt0, const float* __restrict__ tgt1,
    unsigned* __restrict__ packF,
    unsigned* __restrict__ pL1t, unsigned* __restrict__ pL2t, unsigned* __restrict__ pL3t,
    unsigned* __restrict__ pL1r, unsigned* __restrict__ pL2r, unsigned* __restrict__ pL3r,
    float* __restrict__ out)
{
    int bid = blockIdx.x;          // 24 * 64; i fastest for CU load mixing
    int t = threadIdx.x;
    if (bid == 0 && t == 0) out[0] = 0.0f;
    int i = bid % 3;               // 0=ref 1=tgt0 2=tgt1
    int rem = bid / 3;
    int b = rem & 7;
    int band = rem >> 3;           // 0..63
    const float* img = (i == 0) ? ref : (i == 1) ? tgt0 : tgt1;
    int x4 = t << 2;
    int y0 = band << 3;
    int q = (i - 1) * 8 + b;

    float l1v[4][2][3];            // [rowpair][xpair][ch]
#pragma unroll
    for (int p = 0; p < 4; ++p) {
        float4 a[3], bb[3];
#pragma unroll
        for (int c = 0; c < 3; ++c) {
            const float* pl = img + ((size_t)(b * 3 + c) << 19);
            a[c]  = *(const float4*)(pl + ((y0 + 2 * p) << 10) + x4);
            bb[c] = *(const float4*)(pl + ((y0 + 2 * p + 1) << 10) + x4);
        }
        if (i > 0) {
            unsigned* o = packF + ((size_t)q << 19) + ((y0 + 2 * p) << 10) + x4;
            uint4 v0;
            v0.x = pack_px1(a[0].x, a[1].x, a[2].x);
            v0.y = pack_px1(a[0].y, a[1].y, a[2].y);
            v0.z = pack_px1(a[0].z, a[1].z, a[2].z);
            v0.w = pack_px1(a[0].w, a[1].w, a[2].w);
            *(uint4*)o = v0;
            unsigned* o2 = o + (1 << 10);
            uint4 v1;
            v1.x = pack_px1(bb[0].x, bb[1].x, bb[2].x);
            v1.y = pack_px1(bb[0].y, bb[1].y, bb[2].y);
            v1.z = pack_px1(bb[0].z, bb[1].z, bb[2].z);
            v1.w = pack_px1(bb[0].w, bb[1].w, bb[2].w);
            *(uint4*)o2 = v1;
        }
#pragma unroll
        for (int c = 0; c < 3; ++c) {
            l1v[p][0][c] = (a[c].x + a[c].y + bb[c].x + bb[c].y) * 0.25f;
            l1v[p][1][c] = (a[c].z + a[c].w + bb[c].z + bb[c].w) * 0.25f;
        }
        uint2 d;
        d.x = pack_px1(l1v[p][0][0], l1v[p][0][1], l1v[p][0][2]);
        d.y = pack_px1(l1v[p][1][0], l1v[p][1][1], l1v[p][1][2]);
        unsigned* d1 = ((i == 0) ? pL1r + ((size_t)b << 17) : pL1t + ((size_t)q << 17))
                    + (((band << 2) + p) << 9) + (t << 1);
        *(uint2*)d1 = d;
    }
    float l2v[2][3];
#pragma unroll
    for (int pr = 0; pr < 2; ++pr) {
#pragma unroll
        for (int c = 0; c < 3; ++c)
            l2v[pr][c] = (l1v[2 * pr][0][c] + l1v[2 * pr][1][c] +
                          l1v[2 * pr + 1][0][c] + l1v[2 * pr + 1][1][c]) * 0.25f;
        unsigned* d2 = ((i == 0) ? pL2r + ((size_t)b << 15) : pL2t + ((size_t)q << 15))
                    + (((band << 1) + pr) << 8) + t;
        *d2 = pack_px1(l2v[pr][0], l2v[pr][1], l2v[pr][2]);
    }
    float l3[3];
#pragma unroll
    for (int c = 0; c < 3; ++c) {
        float s = l2v[0][c] + l2v[1][c];
        l3[c] = (s + __shfl_xor(s, 1)) * 0.25f;
    }
    if ((t & 1) == 0) {
        unsigned* d3 = ((i == 0) ? pL3r + ((size_t)b << 13) : pL3t + ((size_t)q << 13))
                    + (band << 7) + (t >> 1);
        *d3 = pack_px1(l3[0], l3[1], l3[2]);
    }
}

// ---------------- packed photometric body, 4 px/thread, 32-tap dword burst ----------------
// Equirect range guarantee: |lon2|<=pi, |lat2|<=pi/2 -> gx in [0,w-1], gy in
// [0,h-1] (up to ~1e-4 fma rounding at the exact edge, where the affected
// bilinear weight is itself ~0). So the reference's OOB zero-masking reduces
// to integer index clamping: no cmp/cndmask weight logic needed (~15% VALU cut,
// and less live state -> fits the 64-VGPR bucket forced by launch_bounds).
template <int SH>
__device__ inline float photo_scale4(int bidl, int tid,
                                     const float* __restrict__ rrF,      // SH==0
                                     const unsigned* __restrict__ rrP,   // SH>0
                                     const float* __restrict__ depth,
                                     const float* __restrict__ mask,
                                     const unsigned* __restrict__ tg,    // planes q=n*8+b
                                     const float* __restrict__ pose,
                                     float* __restrict__ ldsRt) {
    constexpr int h = 512 >> SH;
    constexpr int w = 1024 >> SH;
    constexpr int LOG2W = 10 - SH;
    constexpr int LP = 19 - 2 * SH;
    constexpr float inv_count = 1.0f / (8.0f * 3.0f * h * w);
    constexpr float GXS = (float)((w - 1) / (2.0 * 3.14159265358979323846));
    constexpr float GXB = (float)((w - 1) * 0.5);
    constexpr float GYS = (float)((h - 1) / 3.14159265358979323846);
    constexpr float GYB = (float)((h - 1) * 0.5);

    int lidx = ((bidl << 8) + tid) << 2;
    int b = lidx >> LP;  // block-uniform
    if (tid < 2) make_Rt_to(pose, b * 2 + tid, ldsRt + tid * 12);
    __syncthreads();

    int x0 = lidx & (w - 1);
    int y = (lidx >> LOG2W) & (h - 1);
    int pix = (y << LOG2W) + x0;

    float lat = -(((float)y + 0.5f) * (2.0f / (float)h) - 1.0f) * (0.5f * PI_F);
    float slat = __sinf(lat), clat = __cosf(lat);

    float4 dep4 = *(const float4*)(depth + ((size_t)b << LP) + pix);
    float dp[4] = {dep4.x, dep4.y, dep4.z, dep4.w};
    float rcv[4][3];
    if constexpr (SH == 0) {
#pragma unroll
        for (int c = 0; c < 3; ++c) {
            float4 rv = *(const float4*)(rrF + ((size_t)(b * 3 + c) << LP) + pix);
            rcv[0][c] = rv.x; rcv[1][c] = rv.y; rcv[2][c] = rv.z; rcv[3][c] = rv.w;
        }
    } else {
        const unsigned* rp = rrP + ((size_t)b << LP) + pix;
        uint4 u = *(const uint4*)rp;
        float3 f0 = unpack_px1(u.x), f1 = unpack_px1(u.y), f2 = unpack_px1(u.z), f3 = unpack_px1(u.w);
        rcv[0][0] = f0.x; rcv[0][1] = f0.y; rcv[0][2] = f0.z;
        rcv[1][0] = f1.x; rcv[1][1] = f1.y; rcv[1][2] = f1.z;
        rcv[2][0] = f2.x; rcv[2][1] = f2.y; rcv[2][2] = f2.z;
        rcv[3][0] = f3.x; rcv[3][1] = f3.y; rcv[3][2] = f3.z;
    }
    float m4[2][4];
#pragma unroll
    for (int n = 0; n < 2; ++n) {
        float4 mv = *(const float4*)(mask + ((size_t)(b * 2 + n) << LP) + pix);
        m4[n][0] = mv.x; m4[n][1] = mv.y; m4[n][2] = mv.z; m4[n][3] = mv.w;
    }

    const unsigned* pl0 = tg + ((size_t)b << LP);
    const unsigned* pl1 = tg + ((size_t)(8 + b) << LP);

    // phase A: all 8 (px,frame) groups' addresses + weights
    float wt[8][4];
    int off[8][4];
#pragma unroll
    for (int i = 0; i < 4; ++i) {
        float lon = (((float)(x0 + i) + 0.5f) * (2.0f / (float)w) - 1.0f) * PI_F;
        float sl = __sinf(lon), cl = __cosf(lon);
        float X = dp[i] * clat * sl, Y = dp[i] * slat, Z = dp[i] * clat * cl;
#pragma unroll
        for (int n = 0; n < 2; ++n) {
            const float* R = ldsRt + n * 12;
            float px = R[0] * X + R[1] * Y + R[2] * Z + R[9];
            float py = R[3] * X + R[4] * Y + R[5] * Z + R[10];
            float pz = R[6] * X + R[7] * Y + R[8] * Z + R[11];
            float rxz = sqrtf(px * px + pz * pz);
            float lon2 = fast_atan2f(px, pz);
            float lat2 = fast_atan2f(py, rxz);
            float gx = fmaf(lon2, GXS, GXB);
            float gy = fmaf(lat2, GYS, GYB);
            float x0f = floorf(gx), y0f = floorf(gy);
            float fx = gx - x0f, fy = gy - y0f;
            int xi0 = max((int)x0f, 0);
            int yi0 = max((int)y0f, 0);
            int xi1 = min(xi0 + 1, w - 1);
            int yi1 = min(yi0 + 1, h - 1);
            int g = i * 2 + n;
            wt[g][0] = (1.0f - fx) * (1.0f - fy);
            wt[g][1] = (1.0f - fx) * fy;
            wt[g][2] = fx * (1.0f - fy);
            wt[g][3] = fx * fy;
            off[g][0] = (yi0 << LOG2W) + xi0;
            off[g][1] = (yi1 << LOG2W) + xi0;
            off[g][2] = (yi0 << LOG2W) + xi1;
            off[g][3] = (yi1 << LOG2W) + xi1;
        }
    }
    // phase B: one 32-load dword burst
    unsigned tap[8][4];
#pragma unroll
    for (int g = 0; g < 8; ++g) {
        const unsigned* P = (g & 1) ? pl1 : pl0;
#pragma unroll
        for (int k = 0; k < 4; ++k) tap[g][k] = P[off[g][k]];
    }
    // phase C: combine
    float acc = 0.0f;
#pragma unroll
    for (int g = 0; g < 8; ++g) {
        int i = g >> 1, n = g & 1;
        float3 ta = unpack_px1(tap[g][0]);
        float3 tb = unpack_px1(tap[g][1]);
        float3 tc = unpack_px1(tap[g][2]);
        float3 td = unpack_px1(tap[g][3]);
        float v0 = wt[g][0] * ta.x + wt[g][1] * tb.x + wt[g][2] * tc.x + wt[g][3] * td.x;
        float v1 = wt[g][0] * ta.y + wt[g][1] * tb.y + wt[g][2] * tc.y + wt[g][3] * td.y;
        float v2 = wt[g][0] * ta.z + wt[g][1] * tb.z + wt[g][2] * tc.z + wt[g][3] * td.z;
        acc += m4[n][i] * (fabsf(rcv[i][0] - v0) + fabsf(rcv[i][1] - v1) + fabsf(rcv[i][2] - v2));
    }
    return acc * inv_count;
}

// __launch_bounds__(256, 8): 8 waves/SIMD -> allocator targets <=64 VGPR,
// crossing the 65..128 bucket (wave cap 16->32/CU). ILP unchanged vs R2.
__global__ __launch_bounds__(256, 8) void photo_all_packed4d(
    const float* __restrict__ rrF,
    const unsigned* __restrict__ rr1, const unsigned* __restrict__ rr2, const unsigned* __restrict__ rr3,
    const float* __restrict__ dep0, const float* __restrict__ msk0,
    const float* __restrict__ dep1, const float* __restrict__ msk1,
    const float* __restrict__ dep2, const float* __restrict__ msk2,
    const float* __restrict__ dep3, const float* __restrict__ msk3,
    const unsigned* __restrict__ packF,
    const unsigned* __restrict__ pL1t, const unsigned* __restrict__ pL2t, const unsigned* __restrict__ pL3t,
    const float* __restrict__ pose, float* __restrict__ out) {
    __shared__ float ldsRt[24];
    __shared__ float wsum[4];
    int bid = blockIdx.x, tid = threadIdx.x;
    float acc;
    // XCD slab swizzle: blocks dispatched round-robin over 8 XCDs -> give each
    // XCD a contiguous slab (== one batch b at every scale) for L2 tap locality.
    if (bid < 4096) {
        int s = ((bid & 7) << 9) | (bid >> 3);
        acc = photo_scale4<0>(s, tid, rrF, nullptr, dep0, msk0, packF, pose, ldsRt);
    } else if (bid < 5120) {
        int t0 = bid - 4096;
        int s = ((t0 & 7) << 7) | (t0 >> 3);
        acc = photo_scale4<1>(s, tid, nullptr, rr1, dep1, msk1, pL1t, pose, ldsRt);
    } else if (bid < 5376) {
        int t0 = bid - 5120;
        int s = ((t0 & 7) << 5) | (t0 >> 3);
        acc = photo_scale4<2>(s, tid, nullptr, rr2, dep2, msk2, pL2t, pose, ldsRt);
    } else {
        int t0 = bid - 5376;
        int s = ((t0 & 7) << 3) | (t0 >> 3);
        acc = photo_scale4<3>(s, tid, nullptr, rr3, dep3, msk3, pL3t, pose, ldsRt);
    }

    for (int off = 32; off > 0; off >>= 1) acc += __shfl_down(acc, off);
    if ((tid & 63) == 0) wsum[tid >> 6] = acc;
    __syncthreads();
    if (tid == 0) atomicAdd(out, wsum[0] + wsum[1] + wsum[2] + wsum[3]);
}

// ================= fallback path (round-3 proven fp32 kernels) =================
template <int LWD>
__global__ __launch_bounds__(256) void down3_kernel(const float* __restrict__ sA,
                                                    const float* __restrict__ sB,
                                                    const float* __restrict__ sC,
                                                    float* __restrict__ dA,
                                                    float* __restrict__ dB,
                                                    float* __restrict__ dC) {
    const float* src = (blockIdx.y == 0) ? sA : (blockIdx.y == 1) ? sB : sC;
    float* dst = (blockIdx.y == 0) ? dA : (blockIdx.y == 1) ? dB : dC;
    int idx = blockIdx.x * 256 + threadIdx.x;
    constexpr int HB = LWD - 1;
    int xp = idx & ((1 << HB) - 1);
    int y = (idx >> HB) & ((1 << HB) - 1);
    int c = idx >> (2 * HB);
    const float* sp = src + ((size_t)c << (2 * LWD + 1)) + ((size_t)(2 * y) << (LWD + 1)) + 4 * xp;
    float4 r0 = *(const float4*)sp;
    float4 r1 = *(const float4*)(sp + (1 << (LWD + 1)));
    float2 d;
    d.x = 0.25f * (r0.x + r0.y + r1.x + r1.y);
    d.y = 0.25f * (r0.z + r0.w + r1.z + r1.w);
    *(float2*)(dst + ((size_t)c << (2 * LWD - 1)) + ((size_t)y << LWD) + 2 * xp) = d;
}

template <int SH>
__device__ inline float photo_scale(int bidl, int tid,
                                    const float* __restrict__ rr,
                                    const float* __restrict__ depth,
                                    const float* __restrict__ mask,
                                    const float* __restrict__ tg0,
                                    const float* __restrict__ tg1,
                                    const float* __restrict__ pose,
                                    float* __restrict__ ldsRt) {
    constexpr int h = 512 >> SH;
    constexpr int w = 1024 >> SH;
    constexpr int LOG2W = 10 - SH;
    constexpr int LP = 19 - 2 * SH;
    constexpr float inv_count = 1.0f / (8.0f * 3.0f * h * w);
    int lidx = (bidl << 8) + tid;
    int b = lidx >> LP;
    if (tid < 2) make_Rt_to(pose, b * 2 + tid, ldsRt + tid * 12);
    __syncthreads();
    int x = lidx & (w - 1);
    int y = (lidx >> LOG2W) & (h - 1);
    int pix = (y << LOG2W) + x;
    float lon = (((float)x + 0.5f) * (2.0f / (float)w) - 1.0f) * PI_F;
    float lat = -(((float)y + 0.5f) * (2.0f / (float)h) - 1.0f) * (0.5f * PI_F);
    float sl = __sinf(lon), cl = __cosf(lon);
    float slat = __sinf(lat), clat = __cosf(lat);
    float dep = depth[((size_t)b << LP) + pix];
    float X = dep * clat * sl, Y = dep * slat, Z = dep * clat * cl;
    float rc[3];
#pragma unroll
    for (int c = 0; c < 3; ++c)
        rc[c] = rr[((size_t)(b * 3 + c) << LP) + pix];
    float acc = 0.0f;
#pragma unroll
    for (int n = 0; n < 2; ++n) {
        const float* R = ldsRt + n * 12;
        float px = R[0] * X + R[1] * Y + R[2] * Z + R[9];
        float py = R[3] * X + R[4] * Y + R[5] * Z + R[10];
        float pz = R[6] * X + R[7] * Y + R[8] * Z + R[11];
        float rxz = sqrtf(px * px + pz * pz);
        float lon2 = fast_atan2f(px, pz);
        float lat2 = fast_atan2f(py, rxz);
        float gx = (lon2 * (1.0f / PI_F) + 1.0f) * 0.5f * (float)(w - 1);
        float gy = (lat2 * (2.0f / PI_F) + 1.0f) * 0.5f * (float)(h - 1);
        float x0f = floorf(gx), y0f = floorf(gy);
        float fx = gx - x0f, fy = gy - y0f;
        float wa = (1.0f - fx) * (1.0f - fy);
        float wb = (1.0f - fx) * fy;
        float wc = fx * (1.0f - fy);
        float wd = fx * fy;
        bool vx0 = (x0f >= 0.0f) && (x0f <= (float)(w - 1));
        bool vx1 = (x0f >= -1.0f) && (x0f <= (float)(w - 2));
        bool vy0 = (y0f >= 0.0f) && (y0f <= (float)(h - 1));
        bool vy1 = (y0f >= -1.0f) && (y0f <= (float)(h - 2));
        int xi0 = (int)fminf(fmaxf(x0f, 0.0f), (float)(w - 1));
        int xi1 = (int)fminf(fmaxf(x0f + 1.0f, 0.0f), (float)(w - 1));
        int yi0 = (int)fminf(fmaxf(y0f, 0.0f), (float)(h - 1));
        int yi1 = (int)fminf(fmaxf(y0f + 1.0f, 0.0f), (float)(h - 1));
        float waf = (vx0 && vy0) ? wa : 0.0f;
        float wbf = (vx0 && vy1) ? wb : 0.0f;
        float wcf = (vx1 && vy0) ? wc : 0.0f;
        float wdf = (vx1 && vy1) ? wd : 0.0f;
        int ia = (yi0 << LOG2W) + xi0;
        int ib2 = (yi1 << LOG2W) + xi0;
        int ic = (yi0 << LOG2W) + xi1;
        int id = (yi1 << LOG2W) + xi1;
        const float* tg = (n == 0) ? tg0 : tg1;
        float m = mask[((size_t)(b * 2 + n) << LP) + pix];
#pragma unroll
        for (int c = 0; c < 3; ++c) {
            const float* plane = tg + ((size_t)(b * 3 + c) << LP);
            float v = waf * plane[ia] + wbf * plane[ib2] + wcf * plane[ic] + wdf * plane[id];
            acc += m * fabsf(rc[c] - v);
        }
    }
    return acc * inv_count;
}

__global__ __launch_bounds__(256) void photo_all_kernel(
    const float* __restrict__ rr0, const float* __restrict__ dep0, const float* __restrict__ msk0,
    const float* __restrict__ tA0, const float* __restrict__ tB0,
    const float* __restrict__ rr1, const float* __restrict__ dep1, const float* __restrict__ msk1,
    const float* __restrict__ tA1, const float* __restrict__ tB1,
    const float* __restrict__ rr2, const float* __restrict__ dep2, const float* __restrict__ msk2,
    const float* __restrict__ tA2, const float* __restrict__ tB2,
    const float* __restrict__ rr3, const float* __restrict__ dep3, const float* __restrict__ msk3,
    const float* __restrict__ tA3, const float* __restrict__ tB3,
    const float* __restrict__ pose, float* __restrict__ out) {
    __shared__ float ldsRt[24];
    __shared__ float wsum[4];
    int bid = blockIdx.x, tid = threadIdx.x;
    float acc;
    if (bid < 16384)
        acc = photo_scale<0>(bid, tid, rr0, dep0, msk0, tA0, tB0, pose, ldsRt);
    else if (bid < 20480)
        acc = photo_scale<1>(bid - 16384, tid, rr1, dep1, msk1, tA1, tB1, pose, ldsRt);
    else if (bid < 21504)
        acc = photo_scale<2>(bid - 20480, tid, rr2, dep2, msk2, tA2, tB2, pose, ldsRt);
    else
        acc = photo_scale<3>(bid - 21504, tid, rr3, dep3, msk3, tA3, tB3, pose, ldsRt);
    for (int off = 32; off > 0; off >>= 1) acc += __shfl_down(acc, off);
    if ((tid & 63) == 0) wsum[tid >> 6] = acc;
    __syncthreads();
    if (tid == 0) atomicAdd(out, wsum[0] + wsum[1] + wsum[2] + wsum[3]);
}

extern "C" void kernel_launch(void* const* d_in, const int* in_sizes, int n_in,
                              void* d_out, int out_size, void* d_ws, size_t ws_size,
                              hipStream_t stream) {
    // dict order: ref_rgb, (ref_depth{i}, exp_mask{i}) i=0..3, tgt_rgb0, tgt_rgb1, pose
    const float* ref  = (const float*)d_in[0];
    const float* dep0 = (const float*)d_in[1];
    const float* msk0 = (const float*)d_in[2];
    const float* dep1 = (const float*)d_in[3];
    const float* msk1 = (const float*)d_in[4];
    const float* dep2 = (const float*)d_in[5];
    const float* msk2 = (const float*)d_in[6];
    const float* dep3 = (const float*)d_in[7];
    const float* msk3 = (const float*)d_in[8];
    const float* tgt0 = (const float*)d_in[9];
    const float* tgt1 = (const float*)d_in[10];
    const float* pose = (const float*)d_in[11];
    float* out = (float*)d_out;

    const size_t E_F   = (size_t)16 << 19;
    const size_t E_L1t = (size_t)16 << 17;
    const size_t E_L2t = (size_t)16 << 15;
    const size_t E_L3t = (size_t)16 << 13;
    const size_t E_L1r = (size_t)8 << 17;
    const size_t E_L2r = (size_t)8 << 15;
    const size_t E_L3r = (size_t)8 << 13;
    const size_t NEED_PACKED = (E_F + E_L1t + E_L2t + E_L3t + E_L1r + E_L2r + E_L3r) * sizeof(unsigned);

    const size_t L1 = (size_t)24 * 256 * 512;
    const size_t L2 = (size_t)24 * 128 * 256;
    const size_t L3 = (size_t)24 * 64 * 128;
    const size_t NEED_A = 3 * (L1 + L2 + L3) * sizeof(float);

    if (ws_size >= NEED_PACKED) {
        unsigned* p = (unsigned*)d_ws;
        unsigned* packF = p; p += E_F;
        unsigned* pL1t = p; p += E_L1t;
        unsigned* pL2t = p; p += E_L2t;
        unsigned* pL3t = p; p += E_L3t;
        unsigned* pL1r = p; p += E_L1r;
        unsigned* pL2r = p; p += E_L2r;
        unsigned* pL3r = p; p += E_L3r;

        prep_kernel<<<1536, 256, 0, stream>>>(ref, tgt0, tgt1, packF,
                                              pL1t, pL2t, pL3t, pL1r, pL2r, pL3r, out);
        photo_all_packed4d<<<5440, 256, 0, stream>>>(
            ref, pL1r, pL2r, pL3r,
            dep0, msk0, dep1, msk1, dep2, msk2, dep3, msk3,
            packF, pL1t, pL2t, pL3t, pose, out);
    } else if (ws_size >= NEED_A) {
        hipMemsetAsync(out, 0, sizeof(float), stream);
        float* p = (float*)d_ws;
        float* ref_l1 = p; p += L1;
        float* ref_l2 = p; p += L2;
        float* ref_l3 = p; p += L3;
        float* t0_l1 = p; p += L1;
        float* t0_l2 = p; p += L2;
        float* t0_l3 = p; p += L3;
        float* t1_l1 = p; p += L1;
        float* t1_l2 = p; p += L2;
        float* t1_l3 = p; p += L3;
        down3_kernel<9><<<dim3((24 << 16) / 256, 3), 256, 0, stream>>>(
            ref, tgt0, tgt1, ref_l1, t0_l1, t1_l1);
        down3_kernel<8><<<dim3((24 << 14) / 256, 3), 256, 0, stream>>>(
            ref_l1, t0_l1, t1_l1, ref_l2, t0_l2, t1_l2);
        down3_kernel<7><<<dim3((24 << 12) / 256, 3), 256, 0, stream>>>(
            ref_l2, t0_l2, t1_l2, ref_l3, t0_l3, t1_l3);
        photo_all_kernel<<<21760, 256, 0, stream>>>(
            ref, dep0, msk0, tgt0, tgt1,
            ref_l1, dep1, msk1, t0_l1, t1_l1,
            ref_l2, dep2, msk2, t0_l2, t1_l2,
            ref_l3, dep3, msk3, t0_l3, t1_l3,
            pose, out);
    }
}

// Round 4
// 327.153 us; speedup vs baseline: 1.7878x; 1.7878x over previous
//
#include <hip/hip_runtime.h>
#include <hip/hip_fp16.h>
#include <math.h>

#define PI_F 3.14159265358979323846f

// ---------------- fast atan2 (minimax deg-11, max err ~1e-5 rad) ----------------
// Note: poly(a) >= 0 for a in [0,1], so |result| <= pi exactly (needed by the
// clamp-only bilinear edge handling in photo_scale4).
__device__ inline float fast_atan2f(float y, float x) {
    float ax = fabsf(x), ay = fabsf(y);
    float mx = fmaxf(ax, ay);
    float mn = fminf(ax, ay);
    float a = __fdividef(mn, fmaxf(mx, 1e-30f));
    float s = a * a;
    float r = fmaf(s, fmaf(s, fmaf(s, fmaf(s, fmaf(s, -0.01172120f, 0.05265332f),
                   -0.11643287f), 0.19354346f), -0.33262347f), 0.99997726f);
    r = r * a;
    if (ay > ax) r = 1.57079632679f - r;
    if (x < 0.0f) r = PI_F - r;
    return copysignf(r, y);
}

// Rodrigues: pose (tx,ty,tz,rx,ry,rz) -> o[0..8]=R row-major, o[9..11]=t
__device__ inline void make_Rt_to(const float* __restrict__ pose, int bn, float* __restrict__ o) {
    const float* p = pose + bn * 6;
    float tx = p[0], ty = p[1], tz = p[2];
    float rx = p[3], ry = p[4], rz = p[5];
    float theta = sqrtf(rx * rx + ry * ry + rz * rz);
    float inv = __fdividef(1.0f, fmaxf(theta, 1e-8f));
    float kx = rx * inv, ky = ry * inv, kz = rz * inv;
    float s, c;
    __sincosf(theta, &s, &c);
    float oc = 1.0f - c;
    o[0] = 1.0f - oc * (ky * ky + kz * kz);
    o[1] = -s * kz + oc * kx * ky;
    o[2] =  s * ky + oc * kx * kz;
    o[3] =  s * kz + oc * kx * ky;
    o[4] = 1.0f - oc * (kx * kx + kz * kz);
    o[5] = -s * kx + oc * ky * kz;
    o[6] = -s * ky + oc * kx * kz;
    o[7] =  s * kx + oc * ky * kz;
    o[8] = 1.0f - oc * (kx * kx + ky * ky);
    o[9] = tx; o[10] = ty; o[11] = tz;
}

// ---------------- 11-11-10 fixed-point RGB packing (4 B / pixel) ----------------
__device__ inline unsigned pack_px1(float r, float g, float b) {
    unsigned ri = __float2uint_rn(__saturatef(r) * 2047.0f);
    unsigned gi = __float2uint_rn(__saturatef(g) * 2047.0f);
    unsigned bi = __float2uint_rn(__saturatef(b) * 1023.0f);
    return ri | (gi << 11) | (bi << 22);
}
__device__ inline float3 unpack_px1(unsigned u) {
    float r = (float)(u & 2047u) * (1.0f / 2047.0f);
    float g = (float)((u >> 11) & 2047u) * (1.0f / 2047.0f);
    float b = (float)(u >> 22) * (1.0f / 1023.0f);
    return make_float3(r, g, b);
}

// ---------------- prep: streaming row-band pass (also zeroes out[0]) -----------
__global__ __launch_bounds__(256) void prep_kernel(
    const float* __restrict__ ref, const float* __restrict__ tgt0, const float* __restrict__ tgt1,
    unsigned* __restrict__ packF,
    unsigned* __restrict__ pL1t, unsigned* __restrict__ pL2t, unsigned* __restrict__ pL3t,
    unsigned* __restrict__ pL1r, unsigned* __restrict__ pL2r, unsigned* __restrict__ pL3r,
    float* __restrict__ out)
{
    int bid = blockIdx.x;          // 24 * 64; i fastest for CU load mixing
    int t = threadIdx.x;
    if (bid == 0 && t == 0) out[0] = 0.0f;
    int i = bid % 3;               // 0=ref 1=tgt0 2=tgt1
    int rem = bid / 3;
    int b = rem & 7;
    int band = rem >> 3;           // 0..63
    const float* img = (i == 0) ? ref : (i == 1) ? tgt0 : tgt1;
    int x4 = t << 2;
    int y0 = band << 3;
    int q = (i - 1) * 8 + b;

    float l1v[4][2][3];            // [rowpair][xpair][ch]
#pragma unroll
    for (int p = 0; p < 4; ++p) {
        float4 a[3], bb[3];
#pragma unroll
        for (int c = 0; c < 3; ++c) {
            const float* pl = img + ((size_t)(b * 3 + c) << 19);
            a[c]  = *(const float4*)(pl + ((y0 + 2 * p) << 10) + x4);
            bb[c] = *(const float4*)(pl + ((y0 + 2 * p + 1) << 10) + x4);
        }
        if (i > 0) {
            unsigned* o = packF + ((size_t)q << 19) + ((y0 + 2 * p) << 10) + x4;
            uint4 v0;
            v0.x = pack_px1(a[0].x, a[1].x, a[2].x);
            v0.y = pack_px1(a[0].y, a[1].y, a[2].y);
            v0.z = pack_px1(a[0].z, a[1].z, a[2].z);
            v0.w = pack_px1(a[0].w, a[1].w, a[2].w);
            *(uint4*)o = v0;
            unsigned* o2 = o + (1 << 10);
            uint4 v1;
            v1.x = pack_px1(bb[0].x, bb[1].x, bb[2].x);
            v1.y = pack_px1(bb[0].y, bb[1].y, bb[2].y);
            v1.z = pack_px1(bb[0].z, bb[1].z, bb[2].z);
            v1.w = pack_px1(bb[0].w, bb[1].w, bb[2].w);
            *(uint4*)o2 = v1;
        }
#pragma unroll
        for (int c = 0; c < 3; ++c) {
            l1v[p][0][c] = (a[c].x + a[c].y + bb[c].x + bb[c].y) * 0.25f;
            l1v[p][1][c] = (a[c].z + a[c].w + bb[c].z + bb[c].w) * 0.25f;
        }
        uint2 d;
        d.x = pack_px1(l1v[p][0][0], l1v[p][0][1], l1v[p][0][2]);
        d.y = pack_px1(l1v[p][1][0], l1v[p][1][1], l1v[p][1][2]);
        unsigned* d1 = ((i == 0) ? pL1r + ((size_t)b << 17) : pL1t + ((size_t)q << 17))
                    + (((band << 2) + p) << 9) + (t << 1);
        *(uint2*)d1 = d;
    }
    float l2v[2][3];
#pragma unroll
    for (int pr = 0; pr < 2; ++pr) {
#pragma unroll
        for (int c = 0; c < 3; ++c)
            l2v[pr][c] = (l1v[2 * pr][0][c] + l1v[2 * pr][1][c] +
                          l1v[2 * pr + 1][0][c] + l1v[2 * pr + 1][1][c]) * 0.25f;
        unsigned* d2 = ((i == 0) ? pL2r + ((size_t)b << 15) : pL2t + ((size_t)q << 15))
                    + (((band << 1) + pr) << 8) + t;
        *d2 = pack_px1(l2v[pr][0], l2v[pr][1], l2v[pr][2]);
    }
    float l3[3];
#pragma unroll
    for (int c = 0; c < 3; ++c) {
        float s = l2v[0][c] + l2v[1][c];
        l3[c] = (s + __shfl_xor(s, 1)) * 0.25f;
    }
    if ((t & 1) == 0) {
        unsigned* d3 = ((i == 0) ? pL3r + ((size_t)b << 13) : pL3t + ((size_t)q << 13))
                    + (band << 7) + (t >> 1);
        *d3 = pack_px1(l3[0], l3[1], l3[2]);
    }
}

// ---------------- packed photometric body, 4 px/thread, 32-tap dword burst ----------------
// Equirect range guarantee: |lon2|<=pi, |lat2|<=pi/2 -> gx in [0,w-1], gy in
// [0,h-1] (up to ~1e-4 fma rounding at the exact edge, where the affected
// bilinear weight is itself ~0). So the reference's OOB zero-masking reduces
// to integer index clamping: no cmp/cndmask weight logic needed.
// NOTE (R3 post-mortem): do NOT add a min-waves launch_bounds here — the
// allocator clamped to 32 VGPR and spilled the whole tap state (WRITE_SIZE
// 170 KB -> 706 MB, dur 3x). The 32-tap burst needs its natural ~64-68 VGPR.
template <int SH>
__device__ inline float photo_scale4(int bidl, int tid,
                                     const float* __restrict__ rrF,      // SH==0
                                     const unsigned* __restrict__ rrP,   // SH>0
                                     const float* __restrict__ depth,
                                     const float* __restrict__ mask,
                                     const unsigned* __restrict__ tg,    // planes q=n*8+b
                                     const float* __restrict__ pose,
                                     float* __restrict__ ldsRt) {
    constexpr int h = 512 >> SH;
    constexpr int w = 1024 >> SH;
    constexpr int LOG2W = 10 - SH;
    constexpr int LP = 19 - 2 * SH;
    constexpr float inv_count = 1.0f / (8.0f * 3.0f * h * w);
    constexpr float GXS = (float)((w - 1) / (2.0 * 3.14159265358979323846));
    constexpr float GXB = (float)((w - 1) * 0.5);
    constexpr float GYS = (float)((h - 1) / 3.14159265358979323846);
    constexpr float GYB = (float)((h - 1) * 0.5);

    int lidx = ((bidl << 8) + tid) << 2;
    int b = lidx >> LP;  // block-uniform
    if (tid < 2) make_Rt_to(pose, b * 2 + tid, ldsRt + tid * 12);
    __syncthreads();

    int x0 = lidx & (w - 1);
    int y = (lidx >> LOG2W) & (h - 1);
    int pix = (y << LOG2W) + x0;

    float lat = -(((float)y + 0.5f) * (2.0f / (float)h) - 1.0f) * (0.5f * PI_F);
    float slat = __sinf(lat), clat = __cosf(lat);

    float4 dep4 = *(const float4*)(depth + ((size_t)b << LP) + pix);
    float dp[4] = {dep4.x, dep4.y, dep4.z, dep4.w};
    float rcv[4][3];
    if constexpr (SH == 0) {
#pragma unroll
        for (int c = 0; c < 3; ++c) {
            float4 rv = *(const float4*)(rrF + ((size_t)(b * 3 + c) << LP) + pix);
            rcv[0][c] = rv.x; rcv[1][c] = rv.y; rcv[2][c] = rv.z; rcv[3][c] = rv.w;
        }
    } else {
        const unsigned* rp = rrP + ((size_t)b << LP) + pix;
        uint4 u = *(const uint4*)rp;
        float3 f0 = unpack_px1(u.x), f1 = unpack_px1(u.y), f2 = unpack_px1(u.z), f3 = unpack_px1(u.w);
        rcv[0][0] = f0.x; rcv[0][1] = f0.y; rcv[0][2] = f0.z;
        rcv[1][0] = f1.x; rcv[1][1] = f1.y; rcv[1][2] = f1.z;
        rcv[2][0] = f2.x; rcv[2][1] = f2.y; rcv[2][2] = f2.z;
        rcv[3][0] = f3.x; rcv[3][1] = f3.y; rcv[3][2] = f3.z;
    }
    float m4[2][4];
#pragma unroll
    for (int n = 0; n < 2; ++n) {
        float4 mv = *(const float4*)(mask + ((size_t)(b * 2 + n) << LP) + pix);
        m4[n][0] = mv.x; m4[n][1] = mv.y; m4[n][2] = mv.z; m4[n][3] = mv.w;
    }

    const unsigned* pl0 = tg + ((size_t)b << LP);
    const unsigned* pl1 = tg + ((size_t)(8 + b) << LP);

    // phase A: all 8 (px,frame) groups' addresses + weights
    float wt[8][4];
    int off[8][4];
#pragma unroll
    for (int i = 0; i < 4; ++i) {
        float lon = (((float)(x0 + i) + 0.5f) * (2.0f / (float)w) - 1.0f) * PI_F;
        float sl = __sinf(lon), cl = __cosf(lon);
        float X = dp[i] * clat * sl, Y = dp[i] * slat, Z = dp[i] * clat * cl;
#pragma unroll
        for (int n = 0; n < 2; ++n) {
            const float* R = ldsRt + n * 12;
            float px = R[0] * X + R[1] * Y + R[2] * Z + R[9];
            float py = R[3] * X + R[4] * Y + R[5] * Z + R[10];
            float pz = R[6] * X + R[7] * Y + R[8] * Z + R[11];
            float rxz = sqrtf(px * px + pz * pz);
            float lon2 = fast_atan2f(px, pz);
            float lat2 = fast_atan2f(py, rxz);
            float gx = fmaf(lon2, GXS, GXB);
            float gy = fmaf(lat2, GYS, GYB);
            float x0f = floorf(gx), y0f = floorf(gy);
            float fx = gx - x0f, fy = gy - y0f;
            int xi0 = max((int)x0f, 0);
            int yi0 = max((int)y0f, 0);
            int xi1 = min(xi0 + 1, w - 1);
            int yi1 = min(yi0 + 1, h - 1);
            int g = i * 2 + n;
            wt[g][0] = (1.0f - fx) * (1.0f - fy);
            wt[g][1] = (1.0f - fx) * fy;
            wt[g][2] = fx * (1.0f - fy);
            wt[g][3] = fx * fy;
            off[g][0] = (yi0 << LOG2W) + xi0;
            off[g][1] = (yi1 << LOG2W) + xi0;
            off[g][2] = (yi0 << LOG2W) + xi1;
            off[g][3] = (yi1 << LOG2W) + xi1;
        }
    }
    // phase B: one 32-load dword burst
    unsigned tap[8][4];
#pragma unroll
    for (int g = 0; g < 8; ++g) {
        const unsigned* P = (g & 1) ? pl1 : pl0;
#pragma unroll
        for (int k = 0; k < 4; ++k) tap[g][k] = P[off[g][k]];
    }
    // phase C: combine
    float acc = 0.0f;
#pragma unroll
    for (int g = 0; g < 8; ++g) {
        int i = g >> 1, n = g & 1;
        float3 ta = unpack_px1(tap[g][0]);
        float3 tb = unpack_px1(tap[g][1]);
        float3 tc = unpack_px1(tap[g][2]);
        float3 td = unpack_px1(tap[g][3]);
        float v0 = wt[g][0] * ta.x + wt[g][1] * tb.x + wt[g][2] * tc.x + wt[g][3] * td.x;
        float v1 = wt[g][0] * ta.y + wt[g][1] * tb.y + wt[g][2] * tc.y + wt[g][3] * td.y;
        float v2 = wt[g][0] * ta.z + wt[g][1] * tb.z + wt[g][2] * tc.z + wt[g][3] * td.z;
        acc += m4[n][i] * (fabsf(rcv[i][0] - v0) + fabsf(rcv[i][1] - v1) + fabsf(rcv[i][2] - v2));
    }
    return acc * inv_count;
}

__global__ __launch_bounds__(256) void photo_all_packed4d(
    const float* __restrict__ rrF,
    const unsigned* __restrict__ rr1, const unsigned* __restrict__ rr2, const unsigned* __restrict__ rr3,
    const float* __restrict__ dep0, const float* __restrict__ msk0,
    const float* __restrict__ dep1, const float* __restrict__ msk1,
    const float* __restrict__ dep2, const float* __restrict__ msk2,
    const float* __restrict__ dep3, const float* __restrict__ msk3,
    const unsigned* __restrict__ packF,
    const unsigned* __restrict__ pL1t, const unsigned* __restrict__ pL2t, const unsigned* __restrict__ pL3t,
    const float* __restrict__ pose, float* __restrict__ out) {
    __shared__ float ldsRt[24];
    __shared__ float wsum[4];
    int bid = blockIdx.x, tid = threadIdx.x;
    float acc;
    // XCD slab swizzle: blocks dispatched round-robin over 8 XCDs -> give each
    // XCD a contiguous slab (== one batch b at every scale) for L2 tap locality.
    if (bid < 4096) {
        int s = ((bid & 7) << 9) | (bid >> 3);
        acc = photo_scale4<0>(s, tid, rrF, nullptr, dep0, msk0, packF, pose, ldsRt);
    } else if (bid < 5120) {
        int t0 = bid - 4096;
        int s = ((t0 & 7) << 7) | (t0 >> 3);
        acc = photo_scale4<1>(s, tid, nullptr, rr1, dep1, msk1, pL1t, pose, ldsRt);
    } else if (bid < 5376) {
        int t0 = bid - 5120;
        int s = ((t0 & 7) << 5) | (t0 >> 3);
        acc = photo_scale4<2>(s, tid, nullptr, rr2, dep2, msk2, pL2t, pose, ldsRt);
    } else {
        int t0 = bid - 5376;
        int s = ((t0 & 7) << 3) | (t0 >> 3);
        acc = photo_scale4<3>(s, tid, nullptr, rr3, dep3, msk3, pL3t, pose, ldsRt);
    }

    for (int off = 32; off > 0; off >>= 1) acc += __shfl_down(acc, off);
    if ((tid & 63) == 0) wsum[tid >> 6] = acc;
    __syncthreads();
    if (tid == 0) atomicAdd(out, wsum[0] + wsum[1] + wsum[2] + wsum[3]);
}

// ================= fallback path (round-3 proven fp32 kernels) =================
template <int LWD>
__global__ __launch_bounds__(256) void down3_kernel(const float* __restrict__ sA,
                                                    const float* __restrict__ sB,
                                                    const float* __restrict__ sC,
                                                    float* __restrict__ dA,
                                                    float* __restrict__ dB,
                                                    float* __restrict__ dC) {
    const float* src = (blockIdx.y == 0) ? sA : (blockIdx.y == 1) ? sB : sC;
    float* dst = (blockIdx.y == 0) ? dA : (blockIdx.y == 1) ? dB : dC;
    int idx = blockIdx.x * 256 + threadIdx.x;
    constexpr int HB = LWD - 1;
    int xp = idx & ((1 << HB) - 1);
    int y = (idx >> HB) & ((1 << HB) - 1);
    int c = idx >> (2 * HB);
    const float* sp = src + ((size_t)c << (2 * LWD + 1)) + ((size_t)(2 * y) << (LWD + 1)) + 4 * xp;
    float4 r0 = *(const float4*)sp;
    float4 r1 = *(const float4*)(sp + (1 << (LWD + 1)));
    float2 d;
    d.x = 0.25f * (r0.x + r0.y + r1.x + r1.y);
    d.y = 0.25f * (r0.z + r0.w + r1.z + r1.w);
    *(float2*)(dst + ((size_t)c << (2 * LWD - 1)) + ((size_t)y << LWD) + 2 * xp) = d;
}

template <int SH>
__device__ inline float photo_scale(int bidl, int tid,
                                    const float* __restrict__ rr,
                                    const float* __restrict__ depth,
                                    const float* __restrict__ mask,
                                    const float* __restrict__ tg0,
                                    const float* __restrict__ tg1,
                                    const float* __restrict__ pose,
                                    float* __restrict__ ldsRt) {
    constexpr int h = 512 >> SH;
    constexpr int w = 1024 >> SH;
    constexpr int LOG2W = 10 - SH;
    constexpr int LP = 19 - 2 * SH;
    constexpr float inv_count = 1.0f / (8.0f * 3.0f * h * w);
    int lidx = (bidl << 8) + tid;
    int b = lidx >> LP;
    if (tid < 2) make_Rt_to(pose, b * 2 + tid, ldsRt + tid * 12);
    __syncthreads();
    int x = lidx & (w - 1);
    int y = (lidx >> LOG2W) & (h - 1);
    int pix = (y << LOG2W) + x;
    float lon = (((float)x + 0.5f) * (2.0f / (float)w) - 1.0f) * PI_F;
    float lat = -(((float)y + 0.5f) * (2.0f / (float)h) - 1.0f) * (0.5f * PI_F);
    float sl = __sinf(lon), cl = __cosf(lon);
    float slat = __sinf(lat), clat = __cosf(lat);
    float dep = depth[((size_t)b << LP) + pix];
    float X = dep * clat * sl, Y = dep * slat, Z = dep * clat * cl;
    float rc[3];
#pragma unroll
    for (int c = 0; c < 3; ++c)
        rc[c] = rr[((size_t)(b * 3 + c) << LP) + pix];
    float acc = 0.0f;
#pragma unroll
    for (int n = 0; n < 2; ++n) {
        const float* R = ldsRt + n * 12;
        float px = R[0] * X + R[1] * Y + R[2] * Z + R[9];
        float py = R[3] * X + R[4] * Y + R[5] * Z + R[10];
        float pz = R[6] * X + R[7] * Y + R[8] * Z + R[11];
        float rxz = sqrtf(px * px + pz * pz);
        float lon2 = fast_atan2f(px, pz);
        float lat2 = fast_atan2f(py, rxz);
        float gx = (lon2 * (1.0f / PI_F) + 1.0f) * 0.5f * (float)(w - 1);
        float gy = (lat2 * (2.0f / PI_F) + 1.0f) * 0.5f * (float)(h - 1);
        float x0f = floorf(gx), y0f = floorf(gy);
        float fx = gx - x0f, fy = gy - y0f;
        float wa = (1.0f - fx) * (1.0f - fy);
        float wb = (1.0f - fx) * fy;
        float wc = fx * (1.0f - fy);
        float wd = fx * fy;
        bool vx0 = (x0f >= 0.0f) && (x0f <= (float)(w - 1));
        bool vx1 = (x0f >= -1.0f) && (x0f <= (float)(w - 2));
        bool vy0 = (y0f >= 0.0f) && (y0f <= (float)(h - 1));
        bool vy1 = (y0f >= -1.0f) && (y0f <= (float)(h - 2));
        int xi0 = (int)fminf(fmaxf(x0f, 0.0f), (float)(w - 1));
        int xi1 = (int)fminf(fmaxf(x0f + 1.0f, 0.0f), (float)(w - 1));
        int yi0 = (int)fminf(fmaxf(y0f, 0.0f), (float)(h - 1));
        int yi1 = (int)fminf(fmaxf(y0f + 1.0f, 0.0f), (float)(h - 1));
        float waf = (vx0 && vy0) ? wa : 0.0f;
        float wbf = (vx0 && vy1) ? wb : 0.0f;
        float wcf = (vx1 && vy0) ? wc : 0.0f;
        float wdf = (vx1 && vy1) ? wd : 0.0f;
        int ia = (yi0 << LOG2W) + xi0;
        int ib2 = (yi1 << LOG2W) + xi0;
        int ic = (yi0 << LOG2W) + xi1;
        int id = (yi1 << LOG2W) + xi1;
        const float* tg = (n == 0) ? tg0 : tg1;
        float m = mask[((size_t)(b * 2 + n) << LP) + pix];
#pragma unroll
        for (int c = 0; c < 3; ++c) {
            const float* plane = tg + ((size_t)(b * 3 + c) << LP);
            float v = waf * plane[ia] + wbf * plane[ib2] + wcf * plane[ic] + wdf * plane[id];
            acc += m * fabsf(rc[c] - v);
        }
    }
    return acc * inv_count;
}

__global__ __launch_bounds__(256) void photo_all_kernel(
    const float* __restrict__ rr0, const float* __restrict__ dep0, const float* __restrict__ msk0,
    const float* __restrict__ tA0, const float* __restrict__ tB0,
    const float* __restrict__ rr1, const float* __restrict__ dep1, const float* __restrict__ msk1,
    const float* __restrict__ tA1, const float* __restrict__ tB1,
    const float* __restrict__ rr2, const float* __restrict__ dep2, const float* __restrict__ msk2,
    const float* __restrict__ tA2, const float* __restrict__ tB2,
    const float* __restrict__ rr3, const float* __restrict__ dep3, const float* __restrict__ msk3,
    const float* __restrict__ tA3, const float* __restrict__ tB3,
    const float* __restrict__ pose, float* __restrict__ out) {
    __shared__ float ldsRt[24];
    __shared__ float wsum[4];
    int bid = blockIdx.x, tid = threadIdx.x;
    float acc;
    if (bid < 16384)
        acc = photo_scale<0>(bid, tid, rr0, dep0, msk0, tA0, tB0, pose, ldsRt);
    else if (bid < 20480)
        acc = photo_scale<1>(bid - 16384, tid, rr1, dep1, msk1, tA1, tB1, pose, ldsRt);
    else if (bid < 21504)
        acc = photo_scale<2>(bid - 20480, tid, rr2, dep2, msk2, tA2, tB2, pose, ldsRt);
    else
        acc = photo_scale<3>(bid - 21504, tid, rr3, dep3, msk3, tA3, tB3, pose, ldsRt);
    for (int off = 32; off > 0; off >>= 1) acc += __shfl_down(acc, off);
    if ((tid & 63) == 0) wsum[tid >> 6] = acc;
    __syncthreads();
    if (tid == 0) atomicAdd(out, wsum[0] + wsum[1] + wsum[2] + wsum[3]);
}

extern "C" void kernel_launch(void* const* d_in, const int* in_sizes, int n_in,
                              void* d_out, int out_size, void* d_ws, size_t ws_size,
                              hipStream_t stream) {
    // dict order: ref_rgb, (ref_depth{i}, exp_mask{i}) i=0..3, tgt_rgb0, tgt_rgb1, pose
    const float* ref  = (const float*)d_in[0];
    const float* dep0 = (const float*)d_in[1];
    const float* msk0 = (const float*)d_in[2];
    const float* dep1 = (const float*)d_in[3];
    const float* msk1 = (const float*)d_in[4];
    const float* dep2 = (const float*)d_in[5];
    const float* msk2 = (const float*)d_in[6];
    const float* dep3 = (const float*)d_in[7];
    const float* msk3 = (const float*)d_in[8];
    const float* tgt0 = (const float*)d_in[9];
    const float* tgt1 = (const float*)d_in[10];
    const float* pose = (const float*)d_in[11];
    float* out = (float*)d_out;

    const size_t E_F   = (size_t)16 << 19;
    const size_t E_L1t = (size_t)16 << 17;
    const size_t E_L2t = (size_t)16 << 15;
    const size_t E_L3t = (size_t)16 << 13;
    const size_t E_L1r = (size_t)8 << 17;
    const size_t E_L2r = (size_t)8 << 15;
    const size_t E_L3r = (size_t)8 << 13;
    const size_t NEED_PACKED = (E_F + E_L1t + E_L2t + E_L3t + E_L1r + E_L2r + E_L3r) * sizeof(unsigned);

    const size_t L1 = (size_t)24 * 256 * 512;
    const size_t L2 = (size_t)24 * 128 * 256;
    const size_t L3 = (size_t)24 * 64 * 128;
    const size_t NEED_A = 3 * (L1 + L2 + L3) * sizeof(float);

    if (ws_size >= NEED_PACKED) {
        unsigned* p = (unsigned*)d_ws;
        unsigned* packF = p; p += E_F;
        unsigned* pL1t = p; p += E_L1t;
        unsigned* pL2t = p; p += E_L2t;
        unsigned* pL3t = p; p += E_L3t;
        unsigned* pL1r = p; p += E_L1r;
        unsigned* pL2r = p; p += E_L2r;
        unsigned* pL3r = p; p += E_L3r;

        prep_kernel<<<1536, 256, 0, stream>>>(ref, tgt0, tgt1, packF,
                                              pL1t, pL2t, pL3t, pL1r, pL2r, pL3r, out);
        photo_all_packed4d<<<5440, 256, 0, stream>>>(
            ref, pL1r, pL2r, pL3r,
            dep0, msk0, dep1, msk1, dep2, msk2, dep3, msk3,
            packF, pL1t, pL2t, pL3t, pose, out);
    } else if (ws_size >= NEED_A) {
        hipMemsetAsync(out, 0, sizeof(float), stream);
        float* p = (float*)d_ws;
        float* ref_l1 = p; p += L1;
        float* ref_l2 = p; p += L2;
        float* ref_l3 = p; p += L3;
        float* t0_l1 = p; p += L1;
        float* t0_l2 = p; p += L2;
        float* t0_l3 = p; p += L3;
        float* t1_l1 = p; p += L1;
        float* t1_l2 = p; p += L2;
        float* t1_l3 = p; p += L3;
        down3_kernel<9><<<dim3((24 << 16) / 256, 3), 256, 0, stream>>>(
            ref, tgt0, tgt1, ref_l1, t0_l1, t1_l1);
        down3_kernel<8><<<dim3((24 << 14) / 256, 3), 256, 0, stream>>>(
            ref_l1, t0_l1, t1_l1, ref_l2, t0_l2, t1_l2);
        down3_kernel<7><<<dim3((24 << 12) / 256, 3), 256, 0, stream>>>(
            ref_l2, t0_l2, t1_l2, ref_l3, t0_l3, t1_l3);
        photo_all_kernel<<<21760, 256, 0, stream>>>(
            ref, dep0, msk0, tgt0, tgt1,
            ref_l1, dep1, msk1, t0_l1, t1_l1,
            ref_l2, dep2, msk2, t0_l2, t1_l2,
            ref_l3, dep3, msk3, t0_l3, t1_l3,
            pose, out);
    }
}

// Round 5
// 305.369 us; speedup vs baseline: 1.9153x; 1.0713x over previous
//
#include <hip/hip_runtime.h>
#include <hip/hip_fp16.h>
#include <math.h>

#define PI_F 3.14159265358979323846f

// ---------------- fast atan2 (minimax deg-11, max err ~1e-5 rad) ----------------
// Note: poly(a) >= 0 for a in [0,1], so |result| <= pi exactly (needed by the
// clamp-only bilinear edge handling in photo_scale4).
__device__ inline float fast_atan2f(float y, float x) {
    float ax = fabsf(x), ay = fabsf(y);
    float mx = fmaxf(ax, ay);
    float mn = fminf(ax, ay);
    float a = __fdividef(mn, fmaxf(mx, 1e-30f));
    float s = a * a;
    float r = fmaf(s, fmaf(s, fmaf(s, fmaf(s, fmaf(s, -0.01172120f, 0.05265332f),
                   -0.11643287f), 0.19354346f), -0.33262347f), 0.99997726f);
    r = r * a;
    if (ay > ax) r = 1.57079632679f - r;
    if (x < 0.0f) r = PI_F - r;
    return copysignf(r, y);
}

// Rodrigues: pose (tx,ty,tz,rx,ry,rz) -> o[0..8]=R row-major, o[9..11]=t
__device__ inline void make_Rt_to(const float* __restrict__ pose, int bn, float* __restrict__ o) {
    const float* p = pose + bn * 6;
    float tx = p[0], ty = p[1], tz = p[2];
    float rx = p[3], ry = p[4], rz = p[5];
    float theta = sqrtf(rx * rx + ry * ry + rz * rz);
    float inv = __fdividef(1.0f, fmaxf(theta, 1e-8f));
    float kx = rx * inv, ky = ry * inv, kz = rz * inv;
    float s, c;
    __sincosf(theta, &s, &c);
    float oc = 1.0f - c;
    o[0] = 1.0f - oc * (ky * ky + kz * kz);
    o[1] = -s * kz + oc * kx * ky;
    o[2] =  s * ky + oc * kx * kz;
    o[3] =  s * kz + oc * kx * ky;
    o[4] = 1.0f - oc * (kx * kx + kz * kz);
    o[5] = -s * kx + oc * ky * kz;
    o[6] = -s * ky + oc * kx * kz;
    o[7] =  s * kx + oc * ky * kz;
    o[8] = 1.0f - oc * (kx * kx + ky * ky);
    o[9] = tx; o[10] = ty; o[11] = tz;
}

// ---------------- 11-11-10 fixed-point RGB packing (4 B / pixel) ----------------
__device__ inline unsigned pack_px1(float r, float g, float b) {
    unsigned ri = __float2uint_rn(__saturatef(r) * 2047.0f);
    unsigned gi = __float2uint_rn(__saturatef(g) * 2047.0f);
    unsigned bi = __float2uint_rn(__saturatef(b) * 1023.0f);
    return ri | (gi << 11) | (bi << 22);
}
__device__ inline float3 unpack_px1(unsigned u) {
    float r = (float)(u & 2047u) * (1.0f / 2047.0f);
    float g = (float)((u >> 11) & 2047u) * (1.0f / 2047.0f);
    float b = (float)(u >> 22) * (1.0f / 1023.0f);
    return make_float3(r, g, b);
}

// 8-byte pixel pair with only 4-byte alignment guarantee (xi0 is arbitrary).
// gfx950 supports unaligned global access; worst case clang splits into two
// dword loads (== previous behavior), so this is never worse.
typedef struct __attribute__((packed, aligned(4))) { unsigned x, y; } upair;

// ---------------- prep: streaming row-band pass (also zeroes out[0]) -----------
__global__ __launch_bounds__(256) void prep_kernel(
    const float* __restrict__ ref, const float* __restrict__ tgt0, const float* __restrict__ tgt1,
    unsigned* __restrict__ packF,
    unsigned* __restrict__ pL1t, unsigned* __restrict__ pL2t, unsigned* __restrict__ pL3t,
    unsigned* __restrict__ pL1r, unsigned* __restrict__ pL2r, unsigned* __restrict__ pL3r,
    float* __restrict__ out)
{
    int bid = blockIdx.x;          // 24 * 64; i fastest for CU load mixing
    int t = threadIdx.x;
    if (bid == 0 && t == 0) out[0] = 0.0f;
    int i = bid % 3;               // 0=ref 1=tgt0 2=tgt1
    int rem = bid / 3;
    int b = rem & 7;
    int band = rem >> 3;           // 0..63
    const float* img = (i == 0) ? ref : (i == 1) ? tgt0 : tgt1;
    int x4 = t << 2;
    int y0 = band << 3;
    int q = (i - 1) * 8 + b;

    float l1v[4][2][3];            // [rowpair][xpair][ch]
#pragma unroll
    for (int p = 0; p < 4; ++p) {
        float4 a[3], bb[3];
#pragma unroll
        for (int c = 0; c < 3; ++c) {
            const float* pl = img + ((size_t)(b * 3 + c) << 19);
            a[c]  = *(const float4*)(pl + ((y0 + 2 * p) << 10) + x4);
            bb[c] = *(const float4*)(pl + ((y0 + 2 * p + 1) << 10) + x4);
        }
        if (i > 0) {
            unsigned* o = packF + ((size_t)q << 19) + ((y0 + 2 * p) << 10) + x4;
            uint4 v0;
            v0.x = pack_px1(a[0].x, a[1].x, a[2].x);
            v0.y = pack_px1(a[0].y, a[1].y, a[2].y);
            v0.z = pack_px1(a[0].z, a[1].z, a[2].z);
            v0.w = pack_px1(a[0].w, a[1].w, a[2].w);
            *(uint4*)o = v0;
            unsigned* o2 = o + (1 << 10);
            uint4 v1;
            v1.x = pack_px1(bb[0].x, bb[1].x, bb[2].x);
            v1.y = pack_px1(bb[0].y, bb[1].y, bb[2].y);
            v1.z = pack_px1(bb[0].z, bb[1].z, bb[2].z);
            v1.w = pack_px1(bb[0].w, bb[1].w, bb[2].w);
            *(uint4*)o2 = v1;
        }
#pragma unroll
        for (int c = 0; c < 3; ++c) {
            l1v[p][0][c] = (a[c].x + a[c].y + bb[c].x + bb[c].y) * 0.25f;
            l1v[p][1][c] = (a[c].z + a[c].w + bb[c].z + bb[c].w) * 0.25f;
        }
        uint2 d;
        d.x = pack_px1(l1v[p][0][0], l1v[p][0][1], l1v[p][0][2]);
        d.y = pack_px1(l1v[p][1][0], l1v[p][1][1], l1v[p][1][2]);
        unsigned* d1 = ((i == 0) ? pL1r + ((size_t)b << 17) : pL1t + ((size_t)q << 17))
                    + (((band << 2) + p) << 9) + (t << 1);
        *(uint2*)d1 = d;
    }
    float l2v[2][3];
#pragma unroll
    for (int pr = 0; pr < 2; ++pr) {
#pragma unroll
        for (int c = 0; c < 3; ++c)
            l2v[pr][c] = (l1v[2 * pr][0][c] + l1v[2 * pr][1][c] +
                          l1v[2 * pr + 1][0][c] + l1v[2 * pr + 1][1][c]) * 0.25f;
        unsigned* d2 = ((i == 0) ? pL2r + ((size_t)b << 15) : pL2t + ((size_t)q << 15))
                    + (((band << 1) + pr) << 8) + t;
        *d2 = pack_px1(l2v[pr][0], l2v[pr][1], l2v[pr][2]);
    }
    float l3[3];
#pragma unroll
    for (int c = 0; c < 3; ++c) {
        float s = l2v[0][c] + l2v[1][c];
        l3[c] = (s + __shfl_xor(s, 1)) * 0.25f;
    }
    if ((t & 1) == 0) {
        unsigned* d3 = ((i == 0) ? pL3r + ((size_t)b << 13) : pL3t + ((size_t)q << 13))
                    + (band << 7) + (t >> 1);
        *d3 = pack_px1(l3[0], l3[1], l3[2]);
    }
}

// ---------------- packed photometric body, 4 px/thread, 16 paired taps ----------------
// Bilinear x-neighbors are adjacent dwords -> load each row's pair as ONE 8-byte
// access: 16 VMEM instructions instead of 32 (halves TA/L1 probes), and live
// state across the burst drops ~32 regs (wt[32]->fx/fy[16], off[32]->off[16]).
// xi1-clamp dropped: fx>0 implies xi0<=w-2 (in-bounds); at fx==0 the .y texel
// has zero weight, and the read stays inside the workspace.
// NOTE (R3 post-mortem): do NOT add a min-waves launch_bounds — the allocator
// clamped to 32 VGPR and spilled the tap state (WRITE_SIZE 170 KB -> 706 MB).
template <int SH>
__device__ inline float photo_scale4(int bidl, int tid,
                                     const float* __restrict__ rrF,      // SH==0
                                     const unsigned* __restrict__ rrP,   // SH>0
                                     const float* __restrict__ depth,
                                     const float* __restrict__ mask,
                                     const unsigned* __restrict__ tg,    // planes q=n*8+b
                                     const float* __restrict__ pose,
                                     float* __restrict__ ldsRt) {
    constexpr int h = 512 >> SH;
    constexpr int w = 1024 >> SH;
    constexpr int LOG2W = 10 - SH;
    constexpr int LP = 19 - 2 * SH;
    constexpr float inv_count = 1.0f / (8.0f * 3.0f * h * w);
    constexpr float GXS = (float)((w - 1) / (2.0 * 3.14159265358979323846));
    constexpr float GXB = (float)((w - 1) * 0.5);
    constexpr float GYS = (float)((h - 1) / 3.14159265358979323846);
    constexpr float GYB = (float)((h - 1) * 0.5);

    int lidx = ((bidl << 8) + tid) << 2;
    int b = lidx >> LP;  // block-uniform
    if (tid < 2) make_Rt_to(pose, b * 2 + tid, ldsRt + tid * 12);
    __syncthreads();

    int x0 = lidx & (w - 1);
    int y = (lidx >> LOG2W) & (h - 1);
    int pix = (y << LOG2W) + x0;

    float lat = -(((float)y + 0.5f) * (2.0f / (float)h) - 1.0f) * (0.5f * PI_F);
    float slat = __sinf(lat), clat = __cosf(lat);

    float4 dep4 = *(const float4*)(depth + ((size_t)b << LP) + pix);
    float dp[4] = {dep4.x, dep4.y, dep4.z, dep4.w};
    float rcv[4][3];
    if constexpr (SH == 0) {
#pragma unroll
        for (int c = 0; c < 3; ++c) {
            float4 rv = *(const float4*)(rrF + ((size_t)(b * 3 + c) << LP) + pix);
            rcv[0][c] = rv.x; rcv[1][c] = rv.y; rcv[2][c] = rv.z; rcv[3][c] = rv.w;
        }
    } else {
        const unsigned* rp = rrP + ((size_t)b << LP) + pix;
        uint4 u = *(const uint4*)rp;
        float3 f0 = unpack_px1(u.x), f1 = unpack_px1(u.y), f2 = unpack_px1(u.z), f3 = unpack_px1(u.w);
        rcv[0][0] = f0.x; rcv[0][1] = f0.y; rcv[0][2] = f0.z;
        rcv[1][0] = f1.x; rcv[1][1] = f1.y; rcv[1][2] = f1.z;
        rcv[2][0] = f2.x; rcv[2][1] = f2.y; rcv[2][2] = f2.z;
        rcv[3][0] = f3.x; rcv[3][1] = f3.y; rcv[3][2] = f3.z;
    }
    float m4[2][4];
#pragma unroll
    for (int n = 0; n < 2; ++n) {
        float4 mv = *(const float4*)(mask + ((size_t)(b * 2 + n) << LP) + pix);
        m4[n][0] = mv.x; m4[n][1] = mv.y; m4[n][2] = mv.z; m4[n][3] = mv.w;
    }

    const unsigned* pl0 = tg + ((size_t)b << LP);
    const unsigned* pl1 = tg + ((size_t)(8 + b) << LP);

    // phase A: all 8 (px,frame) groups' addresses + fractional coords
    float fxv[8], fyv[8];
    int off2[8][2];
#pragma unroll
    for (int i = 0; i < 4; ++i) {
        float lon = (((float)(x0 + i) + 0.5f) * (2.0f / (float)w) - 1.0f) * PI_F;
        float sl = __sinf(lon), cl = __cosf(lon);
        float X = dp[i] * clat * sl, Y = dp[i] * slat, Z = dp[i] * clat * cl;
#pragma unroll
        for (int n = 0; n < 2; ++n) {
            const float* R = ldsRt + n * 12;
            float px = R[0] * X + R[1] * Y + R[2] * Z + R[9];
            float py = R[3] * X + R[4] * Y + R[5] * Z + R[10];
            float pz = R[6] * X + R[7] * Y + R[8] * Z + R[11];
            float rxz = sqrtf(px * px + pz * pz);
            float lon2 = fast_atan2f(px, pz);
            float lat2 = fast_atan2f(py, rxz);
            float gx = fmaf(lon2, GXS, GXB);
            float gy = fmaf(lat2, GYS, GYB);
            float x0f = floorf(gx), y0f = floorf(gy);
            int xi0 = max((int)x0f, 0);
            int yi0 = max((int)y0f, 0);
            int yi1 = min(yi0 + 1, h - 1);
            int g = i * 2 + n;
            fxv[g] = gx - x0f;
            fyv[g] = gy - y0f;
            off2[g][0] = (yi0 << LOG2W) + xi0;
            off2[g][1] = (yi1 << LOG2W) + xi0;
        }
    }
    // phase B: one 16-load burst of 8-byte pairs
    upair tp[8][2];
#pragma unroll
    for (int g = 0; g < 8; ++g) {
        const unsigned* P = (g & 1) ? pl1 : pl0;
        tp[g][0] = *(const upair*)(P + off2[g][0]);
        tp[g][1] = *(const upair*)(P + off2[g][1]);
    }
    // phase C: combine (weights recomputed from fx/fy — cheaper than keeping 32 live)
    float acc = 0.0f;
#pragma unroll
    for (int g = 0; g < 8; ++g) {
        int i = g >> 1, n = g & 1;
        float fx = fxv[g], fy = fyv[g];
        float ofx = 1.0f - fx, ofy = 1.0f - fy;
        float w00 = ofx * ofy;   // (yi0, xi0)
        float w01 = ofx * fy;    // (yi1, xi0)
        float w10 = fx * ofy;    // (yi0, xi1)
        float w11 = fx * fy;     // (yi1, xi1)
        float3 ta = unpack_px1(tp[g][0].x);
        float3 tc = unpack_px1(tp[g][0].y);
        float3 tb = unpack_px1(tp[g][1].x);
        float3 td = unpack_px1(tp[g][1].y);
        float v0 = w00 * ta.x + w01 * tb.x + w10 * tc.x + w11 * td.x;
        float v1 = w00 * ta.y + w01 * tb.y + w10 * tc.y + w11 * td.y;
        float v2 = w00 * ta.z + w01 * tb.z + w10 * tc.z + w11 * td.z;
        acc += m4[n][i] * (fabsf(rcv[i][0] - v0) + fabsf(rcv[i][1] - v1) + fabsf(rcv[i][2] - v2));
    }
    return acc * inv_count;
}

__global__ __launch_bounds__(256) void photo_all_packed4p(
    const float* __restrict__ rrF,
    const unsigned* __restrict__ rr1, const unsigned* __restrict__ rr2, const unsigned* __restrict__ rr3,
    const float* __restrict__ dep0, const float* __restrict__ msk0,
    const float* __restrict__ dep1, const float* __restrict__ msk1,
    const float* __restrict__ dep2, const float* __restrict__ msk2,
    const float* __restrict__ dep3, const float* __restrict__ msk3,
    const unsigned* __restrict__ packF,
    const unsigned* __restrict__ pL1t, const unsigned* __restrict__ pL2t, const unsigned* __restrict__ pL3t,
    const float* __restrict__ pose, float* __restrict__ out) {
    __shared__ float ldsRt[24];
    __shared__ float wsum[4];
    int bid = blockIdx.x, tid = threadIdx.x;
    float acc;
    // XCD slab swizzle: blocks dispatched round-robin over 8 XCDs -> give each
    // XCD a contiguous slab (== one batch b at every scale) for L2 tap locality.
    if (bid < 4096) {
        int s = ((bid & 7) << 9) | (bid >> 3);
        acc = photo_scale4<0>(s, tid, rrF, nullptr, dep0, msk0, packF, pose, ldsRt);
    } else if (bid < 5120) {
        int t0 = bid - 4096;
        int s = ((t0 & 7) << 7) | (t0 >> 3);
        acc = photo_scale4<1>(s, tid, nullptr, rr1, dep1, msk1, pL1t, pose, ldsRt);
    } else if (bid < 5376) {
        int t0 = bid - 5120;
        int s = ((t0 & 7) << 5) | (t0 >> 3);
        acc = photo_scale4<2>(s, tid, nullptr, rr2, dep2, msk2, pL2t, pose, ldsRt);
    } else {
        int t0 = bid - 5376;
        int s = ((t0 & 7) << 3) | (t0 >> 3);
        acc = photo_scale4<3>(s, tid, nullptr, rr3, dep3, msk3, pL3t, pose, ldsRt);
    }

    for (int off = 32; off > 0; off >>= 1) acc += __shfl_down(acc, off);
    if ((tid & 63) == 0) wsum[tid >> 6] = acc;
    __syncthreads();
    if (tid == 0) atomicAdd(out, wsum[0] + wsum[1] + wsum[2] + wsum[3]);
}

// ================= fallback path (round-3 proven fp32 kernels) =================
template <int LWD>
__global__ __launch_bounds__(256) void down3_kernel(const float* __restrict__ sA,
                                                    const float* __restrict__ sB,
                                                    const float* __restrict__ sC,
                                                    float* __restrict__ dA,
                                                    float* __restrict__ dB,
                                                    float* __restrict__ dC) {
    const float* src = (blockIdx.y == 0) ? sA : (blockIdx.y == 1) ? sB : sC;
    float* dst = (blockIdx.y == 0) ? dA : (blockIdx.y == 1) ? dB : dC;
    int idx = blockIdx.x * 256 + threadIdx.x;
    constexpr int HB = LWD - 1;
    int xp = idx & ((1 << HB) - 1);
    int y = (idx >> HB) & ((1 << HB) - 1);
    int c = idx >> (2 * HB);
    const float* sp = src + ((size_t)c << (2 * LWD + 1)) + ((size_t)(2 * y) << (LWD + 1)) + 4 * xp;
    float4 r0 = *(const float4*)sp;
    float4 r1 = *(const float4*)(sp + (1 << (LWD + 1)));
    float2 d;
    d.x = 0.25f * (r0.x + r0.y + r1.x + r1.y);
    d.y = 0.25f * (r0.z + r0.w + r1.z + r1.w);
    *(float2*)(dst + ((size_t)c << (2 * LWD - 1)) + ((size_t)y << LWD) + 2 * xp) = d;
}

template <int SH>
__device__ inline float photo_scale(int bidl, int tid,
                                    const float* __restrict__ rr,
                                    const float* __restrict__ depth,
                                    const float* __restrict__ mask,
                                    const float* __restrict__ tg0,
                                    const float* __restrict__ tg1,
                                    const float* __restrict__ pose,
                                    float* __restrict__ ldsRt) {
    constexpr int h = 512 >> SH;
    constexpr int w = 1024 >> SH;
    constexpr int LOG2W = 10 - SH;
    constexpr int LP = 19 - 2 * SH;
    constexpr float inv_count = 1.0f / (8.0f * 3.0f * h * w);
    int lidx = (bidl << 8) + tid;
    int b = lidx >> LP;
    if (tid < 2) make_Rt_to(pose, b * 2 + tid, ldsRt + tid * 12);
    __syncthreads();
    int x = lidx & (w - 1);
    int y = (lidx >> LOG2W) & (h - 1);
    int pix = (y << LOG2W) + x;
    float lon = (((float)x + 0.5f) * (2.0f / (float)w) - 1.0f) * PI_F;
    float lat = -(((float)y + 0.5f) * (2.0f / (float)h) - 1.0f) * (0.5f * PI_F);
    float sl = __sinf(lon), cl = __cosf(lon);
    float slat = __sinf(lat), clat = __cosf(lat);
    float dep = depth[((size_t)b << LP) + pix];
    float X = dep * clat * sl, Y = dep * slat, Z = dep * clat * cl;
    float rc[3];
#pragma unroll
    for (int c = 0; c < 3; ++c)
        rc[c] = rr[((size_t)(b * 3 + c) << LP) + pix];
    float acc = 0.0f;
#pragma unroll
    for (int n = 0; n < 2; ++n) {
        const float* R = ldsRt + n * 12;
        float px = R[0] * X + R[1] * Y + R[2] * Z + R[9];
        float py = R[3] * X + R[4] * Y + R[5] * Z + R[10];
        float pz = R[6] * X + R[7] * Y + R[8] * Z + R[11];
        float rxz = sqrtf(px * px + pz * pz);
        float lon2 = fast_atan2f(px, pz);
        float lat2 = fast_atan2f(py, rxz);
        float gx = (lon2 * (1.0f / PI_F) + 1.0f) * 0.5f * (float)(w - 1);
        float gy = (lat2 * (2.0f / PI_F) + 1.0f) * 0.5f * (float)(h - 1);
        float x0f = floorf(gx), y0f = floorf(gy);
        float fx = gx - x0f, fy = gy - y0f;
        float wa = (1.0f - fx) * (1.0f - fy);
        float wb = (1.0f - fx) * fy;
        float wc = fx * (1.0f - fy);
        float wd = fx * fy;
        bool vx0 = (x0f >= 0.0f) && (x0f <= (float)(w - 1));
        bool vx1 = (x0f >= -1.0f) && (x0f <= (float)(w - 2));
        bool vy0 = (y0f >= 0.0f) && (y0f <= (float)(h - 1));
        bool vy1 = (y0f >= -1.0f) && (y0f <= (float)(h - 2));
        int xi0 = (int)fminf(fmaxf(x0f, 0.0f), (float)(w - 1));
        int xi1 = (int)fminf(fmaxf(x0f + 1.0f, 0.0f), (float)(w - 1));
        int yi0 = (int)fminf(fmaxf(y0f, 0.0f), (float)(h - 1));
        int yi1 = (int)fminf(fmaxf(y0f + 1.0f, 0.0f), (float)(h - 1));
        float waf = (vx0 && vy0) ? wa : 0.0f;
        float wbf = (vx0 && vy1) ? wb : 0.0f;
        float wcf = (vx1 && vy0) ? wc : 0.0f;
        float wdf = (vx1 && vy1) ? wd : 0.0f;
        int ia = (yi0 << LOG2W) + xi0;
        int ib2 = (yi1 << LOG2W) + xi0;
        int ic = (yi0 << LOG2W) + xi1;
        int id = (yi1 << LOG2W) + xi1;
        const float* tg = (n == 0) ? tg0 : tg1;
        float m = mask[((size_t)(b * 2 + n) << LP) + pix];
#pragma unroll
        for (int c = 0; c < 3; ++c) {
            const float* plane = tg + ((size_t)(b * 3 + c) << LP);
            float v = waf * plane[ia] + wbf * plane[ib2] + wcf * plane[ic] + wdf * plane[id];
            acc += m * fabsf(rc[c] - v);
        }
    }
    return acc * inv_count;
}

__global__ __launch_bounds__(256) void photo_all_kernel(
    const float* __restrict__ rr0, const float* __restrict__ dep0, const float* __restrict__ msk0,
    const float* __restrict__ tA0, const float* __restrict__ tB0,
    const float* __restrict__ rr1, const float* __restrict__ dep1, const float* __restrict__ msk1,
    const float* __restrict__ tA1, const float* __restrict__ tB1,
    const float* __restrict__ rr2, const float* __restrict__ dep2, const float* __restrict__ msk2,
    const float* __restrict__ tA2, const float* __restrict__ tB2,
    const float* __restrict__ rr3, const float* __restrict__ dep3, const float* __restrict__ msk3,
    const float* __restrict__ tA3, const float* __restrict__ tB3,
    const float* __restrict__ pose, float* __restrict__ out) {
    __shared__ float ldsRt[24];
    __shared__ float wsum[4];
    int bid = blockIdx.x, tid = threadIdx.x;
    float acc;
    if (bid < 16384)
        acc = photo_scale<0>(bid, tid, rr0, dep0, msk0, tA0, tB0, pose, ldsRt);
    else if (bid < 20480)
        acc = photo_scale<1>(bid - 16384, tid, rr1, dep1, msk1, tA1, tB1, pose, ldsRt);
    else if (bid < 21504)
        acc = photo_scale<2>(bid - 20480, tid, rr2, dep2, msk2, tA2, tB2, pose, ldsRt);
    else
        acc = photo_scale<3>(bid - 21504, tid, rr3, dep3, msk3, tA3, tB3, pose, ldsRt);
    for (int off = 32; off > 0; off >>= 1) acc += __shfl_down(acc, off);
    if ((tid & 63) == 0) wsum[tid >> 6] = acc;
    __syncthreads();
    if (tid == 0) atomicAdd(out, wsum[0] + wsum[1] + wsum[2] + wsum[3]);
}

extern "C" void kernel_launch(void* const* d_in, const int* in_sizes, int n_in,
                              void* d_out, int out_size, void* d_ws, size_t ws_size,
                              hipStream_t stream) {
    // dict order: ref_rgb, (ref_depth{i}, exp_mask{i}) i=0..3, tgt_rgb0, tgt_rgb1, pose
    const float* ref  = (const float*)d_in[0];
    const float* dep0 = (const float*)d_in[1];
    const float* msk0 = (const float*)d_in[2];
    const float* dep1 = (const float*)d_in[3];
    const float* msk1 = (const float*)d_in[4];
    const float* dep2 = (const float*)d_in[5];
    const float* msk2 = (const float*)d_in[6];
    const float* dep3 = (const float*)d_in[7];
    const float* msk3 = (const float*)d_in[8];
    const float* tgt0 = (const float*)d_in[9];
    const float* tgt1 = (const float*)d_in[10];
    const float* pose = (const float*)d_in[11];
    float* out = (float*)d_out;

    const size_t E_F   = (size_t)16 << 19;
    const size_t E_L1t = (size_t)16 << 17;
    const size_t E_L2t = (size_t)16 << 15;
    const size_t E_L3t = (size_t)16 << 13;
    const size_t E_L1r = (size_t)8 << 17;
    const size_t E_L2r = (size_t)8 << 15;
    const size_t E_L3r = (size_t)8 << 13;
    const size_t NEED_PACKED = (E_F + E_L1t + E_L2t + E_L3t + E_L1r + E_L2r + E_L3r) * sizeof(unsigned);

    const size_t L1 = (size_t)24 * 256 * 512;
    const size_t L2 = (size_t)24 * 128 * 256;
    const size_t L3 = (size_t)24 * 64 * 128;
    const size_t NEED_A = 3 * (L1 + L2 + L3) * sizeof(float);

    if (ws_size >= NEED_PACKED) {
        unsigned* p = (unsigned*)d_ws;
        unsigned* packF = p; p += E_F;
        unsigned* pL1t = p; p += E_L1t;
        unsigned* pL2t = p; p += E_L2t;
        unsigned* pL3t = p; p += E_L3t;
        unsigned* pL1r = p; p += E_L1r;
        unsigned* pL2r = p; p += E_L2r;
        unsigned* pL3r = p; p += E_L3r;

        prep_kernel<<<1536, 256, 0, stream>>>(ref, tgt0, tgt1, packF,
                                              pL1t, pL2t, pL3t, pL1r, pL2r, pL3r, out);
        photo_all_packed4p<<<5440, 256, 0, stream>>>(
            ref, pL1r, pL2r, pL3r,
            dep0, msk0, dep1, msk1, dep2, msk2, dep3, msk3,
            packF, pL1t, pL2t, pL3t, pose, out);
    } else if (ws_size >= NEED_A) {
        hipMemsetAsync(out, 0, sizeof(float), stream);
        float* p = (float*)d_ws;
        float* ref_l1 = p; p += L1;
        float* ref_l2 = p; p += L2;
        float* ref_l3 = p; p += L3;
        float* t0_l1 = p; p += L1;
        float* t0_l2 = p; p += L2;
        float* t0_l3 = p; p += L3;
        float* t1_l1 = p; p += L1;
        float* t1_l2 = p; p += L2;
        float* t1_l3 = p; p += L3;
        down3_kernel<9><<<dim3((24 << 16) / 256, 3), 256, 0, stream>>>(
            ref, tgt0, tgt1, ref_l1, t0_l1, t1_l1);
        down3_kernel<8><<<dim3((24 << 14) / 256, 3), 256, 0, stream>>>(
            ref_l1, t0_l1, t1_l1, ref_l2, t0_l2, t1_l2);
        down3_kernel<7><<<dim3((24 << 12) / 256, 3), 256, 0, stream>>>(
            ref_l2, t0_l2, t1_l2, ref_l3, t0_l3, t1_l3);
        photo_all_kernel<<<21760, 256, 0, stream>>>(
            ref, dep0, msk0, tgt0, tgt1,
            ref_l1, dep1, msk1, t0_l1, t1_l1,
            ref_l2, dep2, msk2, t0_l2, t1_l2,
            ref_l3, dep3, msk3, t0_l3, t1_l3,
            pose, out);
    }
}

// Round 6
// 305.115 us; speedup vs baseline: 1.9169x; 1.0008x over previous
//
#include <hip/hip_runtime.h>
#include <hip/hip_fp16.h>
#include <math.h>

#define PI_F 3.14159265358979323846f

// ---------------- fast atan2 (minimax deg-11, max err ~1e-5 rad) ----------------
// Note: poly(a) >= 0 for a in [0,1], so |result| <= pi exactly (needed by the
// clamp-only bilinear edge handling in photo_scale4).
__device__ inline float fast_atan2f(float y, float x) {
    float ax = fabsf(x), ay = fabsf(y);
    float mx = fmaxf(ax, ay);
    float mn = fminf(ax, ay);
    float a = __fdividef(mn, fmaxf(mx, 1e-30f));
    float s = a * a;
    float r = fmaf(s, fmaf(s, fmaf(s, fmaf(s, fmaf(s, -0.01172120f, 0.05265332f),
                   -0.11643287f), 0.19354346f), -0.33262347f), 0.99997726f);
    r = r * a;
    if (ay > ax) r = 1.57079632679f - r;
    if (x < 0.0f) r = PI_F - r;
    return copysignf(r, y);
}

// Specialized variant for x >= 0 (the lat path: x = rxz is a norm).
// Same poly, no pi-reflection branch.
__device__ inline float fast_atanp(float y, float x) {
    float ay = fabsf(y);
    float mx = fmaxf(x, ay);
    float mn = fminf(x, ay);
    float a = __fdividef(mn, fmaxf(mx, 1e-30f));
    float s = a * a;
    float r = fmaf(s, fmaf(s, fmaf(s, fmaf(s, fmaf(s, -0.01172120f, 0.05265332f),
                   -0.11643287f), 0.19354346f), -0.33262347f), 0.99997726f);
    r = r * a;
    if (ay > x) r = 1.57079632679f - r;
    return copysignf(r, y);
}

// Rodrigues: pose (tx,ty,tz,rx,ry,rz) -> o[0..8]=R row-major, o[9..11]=t
__device__ inline void make_Rt_to(const float* __restrict__ pose, int bn, float* __restrict__ o) {
    const float* p = pose + bn * 6;
    float tx = p[0], ty = p[1], tz = p[2];
    float rx = p[3], ry = p[4], rz = p[5];
    float theta = sqrtf(rx * rx + ry * ry + rz * rz);
    float inv = __fdividef(1.0f, fmaxf(theta, 1e-8f));
    float kx = rx * inv, ky = ry * inv, kz = rz * inv;
    float s, c;
    __sincosf(theta, &s, &c);
    float oc = 1.0f - c;
    o[0] = 1.0f - oc * (ky * ky + kz * kz);
    o[1] = -s * kz + oc * kx * ky;
    o[2] =  s * ky + oc * kx * kz;
    o[3] =  s * kz + oc * kx * ky;
    o[4] = 1.0f - oc * (kx * kx + kz * kz);
    o[5] = -s * kx + oc * ky * kz;
    o[6] = -s * ky + oc * kx * kz;
    o[7] =  s * kx + oc * ky * kz;
    o[8] = 1.0f - oc * (kx * kx + ky * ky);
    o[9] = tx; o[10] = ty; o[11] = tz;
}

// ---------------- 11-11-10 fixed-point RGB packing (4 B / pixel) ----------------
__device__ inline unsigned pack_px1(float r, float g, float b) {
    unsigned ri = __float2uint_rn(__saturatef(r) * 2047.0f);
    unsigned gi = __float2uint_rn(__saturatef(g) * 2047.0f);
    unsigned bi = __float2uint_rn(__saturatef(b) * 1023.0f);
    return ri | (gi << 11) | (bi << 22);
}
// Field-unit extraction (no dequant muls — scales are folded into the final
// per-group abs-sum; see phase C).
__device__ inline float3 unpack_fields(unsigned u) {
    float r = (float)(u & 2047u);
    float g = (float)((u >> 11) & 2047u);
    float b = (float)(u >> 22);
    return make_float3(r, g, b);
}

// 8-byte pixel pair with only 4-byte alignment guarantee (xi0 is arbitrary).
typedef struct __attribute__((packed, aligned(4))) { unsigned x, y; } upair;

// ---------------- prep: streaming row-band pass (also zeroes out[0]) -----------
__global__ __launch_bounds__(256) void prep_kernel(
    const float* __restrict__ ref, const float* __restrict__ tgt0, const float* __restrict__ tgt1,
    unsigned* __restrict__ packF,
    unsigned* __restrict__ pL1t, unsigned* __restrict__ pL2t, unsigned* __restrict__ pL3t,
    unsigned* __restrict__ pL1r, unsigned* __restrict__ pL2r, unsigned* __restrict__ pL3r,
    float* __restrict__ out)
{
    int bid = blockIdx.x;          // 24 * 64; i fastest for CU load mixing
    int t = threadIdx.x;
    if (bid == 0 && t == 0) out[0] = 0.0f;
    int i = bid % 3;               // 0=ref 1=tgt0 2=tgt1
    int rem = bid / 3;
    int b = rem & 7;
    int band = rem >> 3;           // 0..63
    const float* img = (i == 0) ? ref : (i == 1) ? tgt0 : tgt1;
    int x4 = t << 2;
    int y0 = band << 3;
    int q = (i - 1) * 8 + b;

    float l1v[4][2][3];            // [rowpair][xpair][ch]
#pragma unroll
    for (int p = 0; p < 4; ++p) {
        float4 a[3], bb[3];
#pragma unroll
        for (int c = 0; c < 3; ++c) {
            const float* pl = img + ((size_t)(b * 3 + c) << 19);
            a[c]  = *(const float4*)(pl + ((y0 + 2 * p) << 10) + x4);
            bb[c] = *(const float4*)(pl + ((y0 + 2 * p + 1) << 10) + x4);
        }
        if (i > 0) {
            unsigned* o = packF + ((size_t)q << 19) + ((y0 + 2 * p) << 10) + x4;
            uint4 v0;
            v0.x = pack_px1(a[0].x, a[1].x, a[2].x);
            v0.y = pack_px1(a[0].y, a[1].y, a[2].y);
            v0.z = pack_px1(a[0].z, a[1].z, a[2].z);
            v0.w = pack_px1(a[0].w, a[1].w, a[2].w);
            *(uint4*)o = v0;
            unsigned* o2 = o + (1 << 10);
            uint4 v1;
            v1.x = pack_px1(bb[0].x, bb[1].x, bb[2].x);
            v1.y = pack_px1(bb[0].y, bb[1].y, bb[2].y);
            v1.z = pack_px1(bb[0].z, bb[1].z, bb[2].z);
            v1.w = pack_px1(bb[0].w, bb[1].w, bb[2].w);
            *(uint4*)o2 = v1;
        }
#pragma unroll
        for (int c = 0; c < 3; ++c) {
            l1v[p][0][c] = (a[c].x + a[c].y + bb[c].x + bb[c].y) * 0.25f;
            l1v[p][1][c] = (a[c].z + a[c].w + bb[c].z + bb[c].w) * 0.25f;
        }
        uint2 d;
        d.x = pack_px1(l1v[p][0][0], l1v[p][0][1], l1v[p][0][2]);
        d.y = pack_px1(l1v[p][1][0], l1v[p][1][1], l1v[p][1][2]);
        unsigned* d1 = ((i == 0) ? pL1r + ((size_t)b << 17) : pL1t + ((size_t)q << 17))
                    + (((band << 2) + p) << 9) + (t << 1);
        *(uint2*)d1 = d;
    }
    float l2v[2][3];
#pragma unroll
    for (int pr = 0; pr < 2; ++pr) {
#pragma unroll
        for (int c = 0; c < 3; ++c)
            l2v[pr][c] = (l1v[2 * pr][0][c] + l1v[2 * pr][1][c] +
                          l1v[2 * pr + 1][0][c] + l1v[2 * pr + 1][1][c]) * 0.25f;
        unsigned* d2 = ((i == 0) ? pL2r + ((size_t)b << 15) : pL2t + ((size_t)q << 15))
                    + (((band << 1) + pr) << 8) + t;
        *d2 = pack_px1(l2v[pr][0], l2v[pr][1], l2v[pr][2]);
    }
    float l3[3];
#pragma unroll
    for (int c = 0; c < 3; ++c) {
        float s = l2v[0][c] + l2v[1][c];
        l3[c] = (s + __shfl_xor(s, 1)) * 0.25f;
    }
    if ((t & 1) == 0) {
        unsigned* d3 = ((i == 0) ? pL3r + ((size_t)b << 13) : pL3t + ((size_t)q << 13))
                    + (band << 7) + (t >> 1);
        *d3 = pack_px1(l3[0], l3[1], l3[2]);
    }
}

// ---------------- packed photometric body, 4 px/thread, 16 paired taps ----------------
// R6 VALU-trim package (photo was 50% VALU-busy at R5):
//  - bilinear in integer-field units, dequant scales folded into final abs-sum
//  - rxz via v_rsq (rxz2 * rsq(max(rxz2,eps))) instead of libm sqrtf
//  - lat path uses fast_atanp (x>=0, no pi-reflection)
//  - one __sincosf per thread for lon; per-column step via 4-fma rotation
// NOTE (R3 post-mortem): no min-waves launch_bounds — allocator spills.
template <int SH>
__device__ inline float photo_scale4(int bidl, int tid,
                                     const float* __restrict__ rrF,      // SH==0
                                     const unsigned* __restrict__ rrP,   // SH>0
                                     const float* __restrict__ depth,
                                     const float* __restrict__ mask,
                                     const unsigned* __restrict__ tg,    // planes q=n*8+b
                                     const float* __restrict__ pose,
                                     float* __restrict__ ldsRt) {
    constexpr int h = 512 >> SH;
    constexpr int w = 1024 >> SH;
    constexpr int LOG2W = 10 - SH;
    constexpr int LP = 19 - 2 * SH;
    constexpr float inv_count = 1.0f / (8.0f * 3.0f * h * w);
    constexpr float GXS = (float)((w - 1) / (2.0 * 3.14159265358979323846));
    constexpr float GXB = (float)((w - 1) * 0.5);
    constexpr float GYS = (float)((h - 1) / 3.14159265358979323846);
    constexpr float GYB = (float)((h - 1) * 0.5);
    // column-step rotation constants: cos/sin(2*pi/w)
    constexpr float CDs[4] = {0.9999811752826011f, 0.9999247018391445f,
                              0.9996988186962042f, 0.9987954562051724f};
    constexpr float SDs[4] = {0.006135884649154475f, 0.012271538285719925f,
                              0.024541228522912288f, 0.049067674327418015f};
    constexpr float CD = CDs[SH], SD = SDs[SH];

    int lidx = ((bidl << 8) + tid) << 2;
    int b = lidx >> LP;  // block-uniform
    if (tid < 2) make_Rt_to(pose, b * 2 + tid, ldsRt + tid * 12);
    __syncthreads();

    int x0 = lidx & (w - 1);
    int y = (lidx >> LOG2W) & (h - 1);
    int pix = (y << LOG2W) + x0;

    float lat = -(((float)y + 0.5f) * (2.0f / (float)h) - 1.0f) * (0.5f * PI_F);
    float slat = __sinf(lat), clat = __cosf(lat);

    float4 dep4 = *(const float4*)(depth + ((size_t)b << LP) + pix);
    float dp[4] = {dep4.x, dep4.y, dep4.z, dep4.w};
    // reference pixels in FIELD units (x2047 / x2047 / x1023)
    float rcv[4][3];
    if constexpr (SH == 0) {
#pragma unroll
        for (int c = 0; c < 3; ++c) {
            float F = (c == 2) ? 1023.0f : 2047.0f;
            float4 rv = *(const float4*)(rrF + ((size_t)(b * 3 + c) << LP) + pix);
            rcv[0][c] = rv.x * F; rcv[1][c] = rv.y * F;
            rcv[2][c] = rv.z * F; rcv[3][c] = rv.w * F;
        }
    } else {
        const unsigned* rp = rrP + ((size_t)b << LP) + pix;
        uint4 u = *(const uint4*)rp;
        float3 f0 = unpack_fields(u.x), f1 = unpack_fields(u.y);
        float3 f2 = unpack_fields(u.z), f3 = unpack_fields(u.w);
        rcv[0][0] = f0.x; rcv[0][1] = f0.y; rcv[0][2] = f0.z;
        rcv[1][0] = f1.x; rcv[1][1] = f1.y; rcv[1][2] = f1.z;
        rcv[2][0] = f2.x; rcv[2][1] = f2.y; rcv[2][2] = f2.z;
        rcv[3][0] = f3.x; rcv[3][1] = f3.y; rcv[3][2] = f3.z;
    }
    float m4[2][4];
#pragma unroll
    for (int n = 0; n < 2; ++n) {
        float4 mv = *(const float4*)(mask + ((size_t)(b * 2 + n) << LP) + pix);
        m4[n][0] = mv.x; m4[n][1] = mv.y; m4[n][2] = mv.z; m4[n][3] = mv.w;
    }

    const unsigned* pl0 = tg + ((size_t)b << LP);
    const unsigned* pl1 = tg + ((size_t)(8 + b) << LP);

    // phase A: all 8 (px,frame) groups' addresses + fractional coords
    float fxv[8], fyv[8];
    int off2[8][2];
    float lon0 = (((float)x0 + 0.5f) * (2.0f / (float)w) - 1.0f) * PI_F;
    float sl, cl;
    __sincosf(lon0, &sl, &cl);
#pragma unroll
    for (int i = 0; i < 4; ++i) {
        if (i > 0) {   // rotate (sl,cl) by one column step: 4 fma vs fresh sincos
            float s2 = fmaf(sl, CD, cl * SD);
            float c2 = fmaf(cl, CD, -sl * SD);
            sl = s2; cl = c2;
        }
        float X = dp[i] * (clat * sl);
        float Y = dp[i] * slat;
        float Z = dp[i] * (clat * cl);
#pragma unroll
        for (int n = 0; n < 2; ++n) {
            const float* R = ldsRt + n * 12;
            float px = fmaf(R[0], X, fmaf(R[1], Y, fmaf(R[2], Z, R[9])));
            float py = fmaf(R[3], X, fmaf(R[4], Y, fmaf(R[5], Z, R[10])));
            float pz = fmaf(R[6], X, fmaf(R[7], Y, fmaf(R[8], Z, R[11])));
            float rxz2 = fmaf(px, px, pz * pz);
            float rxz = rxz2 * __frsqrt_rn(fmaxf(rxz2, 1e-30f));   // v_rsq; ==0 stays 0
            float lon2 = fast_atan2f(px, pz);
            float lat2 = fast_atanp(py, rxz);
            float gx = fmaf(lon2, GXS, GXB);
            float gy = fmaf(lat2, GYS, GYB);
            float x0f = floorf(gx), y0f = floorf(gy);
            int xi0 = max((int)x0f, 0);
            int yi0 = max((int)y0f, 0);
            int yi1 = min(yi0 + 1, h - 1);
            int g = i * 2 + n;
            fxv[g] = gx - x0f;
            fyv[g] = gy - y0f;
            off2[g][0] = (yi0 << LOG2W) + xi0;
            off2[g][1] = (yi1 << LOG2W) + xi0;
        }
    }
    // phase B: one 16-load burst of 8-byte pairs
    upair tp[8][2];
#pragma unroll
    for (int g = 0; g < 8; ++g) {
        const unsigned* P = (g & 1) ? pl1 : pl0;
        tp[g][0] = *(const upair*)(P + off2[g][0]);
        tp[g][1] = *(const upair*)(P + off2[g][1]);
    }
    // phase C: integer-field bilinear, scales folded into the final sum
    float acc = 0.0f;
#pragma unroll
    for (int g = 0; g < 8; ++g) {
        int i = g >> 1, n = g & 1;
        float fx = fxv[g], fy = fyv[g];
        float ofx = 1.0f - fx, ofy = 1.0f - fy;
        float w00 = ofx * ofy;   // (yi0, xi0)
        float w01 = ofx * fy;    // (yi1, xi0)
        float w10 = fx * ofy;    // (yi0, xi1)
        float w11 = fx * fy;     // (yi1, xi1)
        float3 ta = unpack_fields(tp[g][0].x);
        float3 tc = unpack_fields(tp[g][0].y);
        float3 tb = unpack_fields(tp[g][1].x);
        float3 td = unpack_fields(tp[g][1].y);
        float d0 = rcv[i][0] - (fmaf(w00, ta.x, fmaf(w01, tb.x, fmaf(w10, tc.x, w11 * td.x))));
        float d1 = rcv[i][1] - (fmaf(w00, ta.y, fmaf(w01, tb.y, fmaf(w10, tc.y, w11 * td.y))));
        float d2 = rcv[i][2] - (fmaf(w00, ta.z, fmaf(w01, tb.z, fmaf(w10, tc.z, w11 * td.z))));
        float t = fabsf(d0) * (1.0f / 2047.0f);
        t = fmaf(fabsf(d1), (1.0f / 2047.0f), t);
        t = fmaf(fabsf(d2), (1.0f / 1023.0f), t);
        acc = fmaf(m4[n][i], t, acc);
    }
    return acc * inv_count;
}

__global__ __launch_bounds__(256) void photo_all_packed4q(
    const float* __restrict__ rrF,
    const unsigned* __restrict__ rr1, const unsigned* __restrict__ rr2, const unsigned* __restrict__ rr3,
    const float* __restrict__ dep0, const float* __restrict__ msk0,
    const float* __restrict__ dep1, const float* __restrict__ msk1,
    const float* __restrict__ dep2, const float* __restrict__ msk2,
    const float* __restrict__ dep3, const float* __restrict__ msk3,
    const unsigned* __restrict__ packF,
    const unsigned* __restrict__ pL1t, const unsigned* __restrict__ pL2t, const unsigned* __restrict__ pL3t,
    const float* __restrict__ pose, float* __restrict__ out) {
    __shared__ float ldsRt[24];
    __shared__ float wsum[4];
    int bid = blockIdx.x, tid = threadIdx.x;
    float acc;
    // XCD slab swizzle: blocks dispatched round-robin over 8 XCDs -> give each
    // XCD a contiguous slab (== one batch b at every scale) for L2 tap locality.
    if (bid < 4096) {
        int s = ((bid & 7) << 9) | (bid >> 3);
        acc = photo_scale4<0>(s, tid, rrF, nullptr, dep0, msk0, packF, pose, ldsRt);
    } else if (bid < 5120) {
        int t0 = bid - 4096;
        int s = ((t0 & 7) << 7) | (t0 >> 3);
        acc = photo_scale4<1>(s, tid, nullptr, rr1, dep1, msk1, pL1t, pose, ldsRt);
    } else if (bid < 5376) {
        int t0 = bid - 5120;
        int s = ((t0 & 7) << 5) | (t0 >> 3);
        acc = photo_scale4<2>(s, tid, nullptr, rr2, dep2, msk2, pL2t, pose, ldsRt);
    } else {
        int t0 = bid - 5376;
        int s = ((t0 & 7) << 3) | (t0 >> 3);
        acc = photo_scale4<3>(s, tid, nullptr, rr3, dep3, msk3, pL3t, pose, ldsRt);
    }

    for (int off = 32; off > 0; off >>= 1) acc += __shfl_down(acc, off);
    if ((tid & 63) == 0) wsum[tid >> 6] = acc;
    __syncthreads();
    if (tid == 0) atomicAdd(out, wsum[0] + wsum[1] + wsum[2] + wsum[3]);
}

// ================= fallback path (round-3 proven fp32 kernels) =================
template <int LWD>
__global__ __launch_bounds__(256) void down3_kernel(const float* __restrict__ sA,
                                                    const float* __restrict__ sB,
                                                    const float* __restrict__ sC,
                                                    float* __restrict__ dA,
                                                    float* __restrict__ dB,
                                                    float* __restrict__ dC) {
    const float* src = (blockIdx.y == 0) ? sA : (blockIdx.y == 1) ? sB : sC;
    float* dst = (blockIdx.y == 0) ? dA : (blockIdx.y == 1) ? dB : dC;
    int idx = blockIdx.x * 256 + threadIdx.x;
    constexpr int HB = LWD - 1;
    int xp = idx & ((1 << HB) - 1);
    int y = (idx >> HB) & ((1 << HB) - 1);
    int c = idx >> (2 * HB);
    const float* sp = src + ((size_t)c << (2 * LWD + 1)) + ((size_t)(2 * y) << (LWD + 1)) + 4 * xp;
    float4 r0 = *(const float4*)sp;
    float4 r1 = *(const float4*)(sp + (1 << (LWD + 1)));
    float2 d;
    d.x = 0.25f * (r0.x + r0.y + r1.x + r1.y);
    d.y = 0.25f * (r0.z + r0.w + r1.z + r1.w);
    *(float2*)(dst + ((size_t)c << (2 * LWD - 1)) + ((size_t)y << LWD) + 2 * xp) = d;
}

template <int SH>
__device__ inline float photo_scale(int bidl, int tid,
                                    const float* __restrict__ rr,
                                    const float* __restrict__ depth,
                                    const float* __restrict__ mask,
                                    const float* __restrict__ tg0,
                                    const float* __restrict__ tg1,
                                    const float* __restrict__ pose,
                                    float* __restrict__ ldsRt) {
    constexpr int h = 512 >> SH;
    constexpr int w = 1024 >> SH;
    constexpr int LOG2W = 10 - SH;
    constexpr int LP = 19 - 2 * SH;
    constexpr float inv_count = 1.0f / (8.0f * 3.0f * h * w);
    int lidx = (bidl << 8) + tid;
    int b = lidx >> LP;
    if (tid < 2) make_Rt_to(pose, b * 2 + tid, ldsRt + tid * 12);
    __syncthreads();
    int x = lidx & (w - 1);
    int y = (lidx >> LOG2W) & (h - 1);
    int pix = (y << LOG2W) + x;
    float lon = (((float)x + 0.5f) * (2.0f / (float)w) - 1.0f) * PI_F;
    float lat = -(((float)y + 0.5f) * (2.0f / (float)h) - 1.0f) * (0.5f * PI_F);
    float sl = __sinf(lon), cl = __cosf(lon);
    float slat = __sinf(lat), clat = __cosf(lat);
    float dep = depth[((size_t)b << LP) + pix];
    float X = dep * clat * sl, Y = dep * slat, Z = dep * clat * cl;
    float rc[3];
#pragma unroll
    for (int c = 0; c < 3; ++c)
        rc[c] = rr[((size_t)(b * 3 + c) << LP) + pix];
    float acc = 0.0f;
#pragma unroll
    for (int n = 0; n < 2; ++n) {
        const float* R = ldsRt + n * 12;
        float px = R[0] * X + R[1] * Y + R[2] * Z + R[9];
        float py = R[3] * X + R[4] * Y + R[5] * Z + R[10];
        float pz = R[6] * X + R[7] * Y + R[8] * Z + R[11];
        float rxz = sqrtf(px * px + pz * pz);
        float lon2 = fast_atan2f(px, pz);
        float lat2 = fast_atan2f(py, rxz);
        float gx = (lon2 * (1.0f / PI_F) + 1.0f) * 0.5f * (float)(w - 1);
        float gy = (lat2 * (2.0f / PI_F) + 1.0f) * 0.5f * (float)(h - 1);
        float x0f = floorf(gx), y0f = floorf(gy);
        float fx = gx - x0f, fy = gy - y0f;
        float wa = (1.0f - fx) * (1.0f - fy);
        float wb = (1.0f - fx) * fy;
        float wc = fx * (1.0f - fy);
        float wd = fx * fy;
        bool vx0 = (x0f >= 0.0f) && (x0f <= (float)(w - 1));
        bool vx1 = (x0f >= -1.0f) && (x0f <= (float)(w - 2));
        bool vy0 = (y0f >= 0.0f) && (y0f <= (float)(h - 1));
        bool vy1 = (y0f >= -1.0f) && (y0f <= (float)(h - 2));
        int xi0 = (int)fminf(fmaxf(x0f, 0.0f), (float)(w - 1));
        int xi1 = (int)fminf(fmaxf(x0f + 1.0f, 0.0f), (float)(w - 1));
        int yi0 = (int)fminf(fmaxf(y0f, 0.0f), (float)(h - 1));
        int yi1 = (int)fminf(fmaxf(y0f + 1.0f, 0.0f), (float)(h - 1));
        float waf = (vx0 && vy0) ? wa : 0.0f;
        float wbf = (vx0 && vy1) ? wb : 0.0f;
        float wcf = (vx1 && vy0) ? wc : 0.0f;
        float wdf = (vx1 && vy1) ? wd : 0.0f;
        int ia = (yi0 << LOG2W) + xi0;
        int ib2 = (yi1 << LOG2W) + xi0;
        int ic = (yi0 << LOG2W) + xi1;
        int id = (yi1 << LOG2W) + xi1;
        const float* tg = (n == 0) ? tg0 : tg1;
        float m = mask[((size_t)(b * 2 + n) << LP) + pix];
#pragma unroll
        for (int c = 0; c < 3; ++c) {
            const float* plane = tg + ((size_t)(b * 3 + c) << LP);
            float v = waf * plane[ia] + wbf * plane[ib2] + wcf * plane[ic] + wdf * plane[id];
            acc += m * fabsf(rc[c] - v);
        }
    }
    return acc * inv_count;
}

__global__ __launch_bounds__(256) void photo_all_kernel(
    const float* __restrict__ rr0, const float* __restrict__ dep0, const float* __restrict__ msk0,
    const float* __restrict__ tA0, const float* __restrict__ tB0,
    const float* __restrict__ rr1, const float* __restrict__ dep1, const float* __restrict__ msk1,
    const float* __restrict__ tA1, const float* __restrict__ tB1,
    const float* __restrict__ rr2, const float* __restrict__ dep2, const float* __restrict__ msk2,
    const float* __restrict__ tA2, const float* __restrict__ tB2,
    const float* __restrict__ rr3, const float* __restrict__ dep3, const float* __restrict__ msk3,
    const float* __restrict__ tA3, const float* __restrict__ tB3,
    const float* __restrict__ pose, float* __restrict__ out) {
    __shared__ float ldsRt[24];
    __shared__ float wsum[4];
    int bid = blockIdx.x, tid = threadIdx.x;
    float acc;
    if (bid < 16384)
        acc = photo_scale<0>(bid, tid, rr0, dep0, msk0, tA0, tB0, pose, ldsRt);
    else if (bid < 20480)
        acc = photo_scale<1>(bid - 16384, tid, rr1, dep1, msk1, tA1, tB1, pose, ldsRt);
    else if (bid < 21504)
        acc = photo_scale<2>(bid - 20480, tid, rr2, dep2, msk2, tA2, tB2, pose, ldsRt);
    else
        acc = photo_scale<3>(bid - 21504, tid, rr3, dep3, msk3, tA3, tB3, pose, ldsRt);
    for (int off = 32; off > 0; off >>= 1) acc += __shfl_down(acc, off);
    if ((tid & 63) == 0) wsum[tid >> 6] = acc;
    __syncthreads();
    if (tid == 0) atomicAdd(out, wsum[0] + wsum[1] + wsum[2] + wsum[3]);
}

extern "C" void kernel_launch(void* const* d_in, const int* in_sizes, int n_in,
                              void* d_out, int out_size, void* d_ws, size_t ws_size,
                              hipStream_t stream) {
    // dict order: ref_rgb, (ref_depth{i}, exp_mask{i}) i=0..3, tgt_rgb0, tgt_rgb1, pose
    const float* ref  = (const float*)d_in[0];
    const float* dep0 = (const float*)d_in[1];
    const float* msk0 = (const float*)d_in[2];
    const float* dep1 = (const float*)d_in[3];
    const float* msk1 = (const float*)d_in[4];
    const float* dep2 = (const float*)d_in[5];
    const float* msk2 = (const float*)d_in[6];
    const float* dep3 = (const float*)d_in[7];
    const float* msk3 = (const float*)d_in[8];
    const float* tgt0 = (const float*)d_in[9];
    const float* tgt1 = (const float*)d_in[10];
    const float* pose = (const float*)d_in[11];
    float* out = (float*)d_out;

    const size_t E_F   = (size_t)16 << 19;
    const size_t E_L1t = (size_t)16 << 17;
    const size_t E_L2t = (size_t)16 << 15;
    const size_t E_L3t = (size_t)16 << 13;
    const size_t E_L1r = (size_t)8 << 17;
    const size_t E_L2r = (size_t)8 << 15;
    const size_t E_L3r = (size_t)8 << 13;
    const size_t NEED_PACKED = (E_F + E_L1t + E_L2t + E_L3t + E_L1r + E_L2r + E_L3r) * sizeof(unsigned);

    const size_t L1 = (size_t)24 * 256 * 512;
    const size_t L2 = (size_t)24 * 128 * 256;
    const size_t L3 = (size_t)24 * 64 * 128;
    const size_t NEED_A = 3 * (L1 + L2 + L3) * sizeof(float);

    if (ws_size >= NEED_PACKED) {
        unsigned* p = (unsigned*)d_ws;
        unsigned* packF = p; p += E_F;
        unsigned* pL1t = p; p += E_L1t;
        unsigned* pL2t = p; p += E_L2t;
        unsigned* pL3t = p; p += E_L3t;
        unsigned* pL1r = p; p += E_L1r;
        unsigned* pL2r = p; p += E_L2r;
        unsigned* pL3r = p; p += E_L3r;

        prep_kernel<<<1536, 256, 0, stream>>>(ref, tgt0, tgt1, packF,
                                              pL1t, pL2t, pL3t, pL1r, pL2r, pL3r, out);
        photo_all_packed4q<<<5440, 256, 0, stream>>>(
            ref, pL1r, pL2r, pL3r,
            dep0, msk0, dep1, msk1, dep2, msk2, dep3, msk3,
            packF, pL1t, pL2t, pL3t, pose, out);
    } else if (ws_size >= NEED_A) {
        hipMemsetAsync(out, 0, sizeof(float), stream);
        float* p = (float*)d_ws;
        float* ref_l1 = p; p += L1;
        float* ref_l2 = p; p += L2;
        float* ref_l3 = p; p += L3;
        float* t0_l1 = p; p += L1;
        float* t0_l2 = p; p += L2;
        float* t0_l3 = p; p += L3;
        float* t1_l1 = p; p += L1;
        float* t1_l2 = p; p += L2;
        float* t1_l3 = p; p += L3;
        down3_kernel<9><<<dim3((24 << 16) / 256, 3), 256, 0, stream>>>(
            ref, tgt0, tgt1, ref_l1, t0_l1, t1_l1);
        down3_kernel<8><<<dim3((24 << 14) / 256, 3), 256, 0, stream>>>(
            ref_l1, t0_l1, t1_l1, ref_l2, t0_l2, t1_l2);
        down3_kernel<7><<<dim3((24 << 12) / 256, 3), 256, 0, stream>>>(
            ref_l2, t0_l2, t1_l2, ref_l3, t0_l3, t1_l3);
        photo_all_kernel<<<21760, 256, 0, stream>>>(
            ref, dep0, msk0, tgt0, tgt1,
            ref_l1, dep1, msk1, t0_l1, t1_l1,
            ref_l2, dep2, msk2, t0_l2, t1_l2,
            ref_l3, dep3, msk3, t0_l3, t1_l3,
            pose, out);
    }
}